// Round 1
// baseline (413.081 us; speedup 1.0000x reference)
//
#include <hip/hip_runtime.h>
#include <hip/hip_bf16.h>
#include <stdint.h>
#include <math.h>

typedef __bf16 bf16_t;
typedef bf16_t bf16x8 __attribute__((ext_vector_type(8)));
typedef float f32x4 __attribute__((ext_vector_type(4)));

#define B_DIM 8
#define N_DIM 2048
#define D_DIM 512
#define QK_SCALE 0.04419417382415922f  /* 1/sqrt(512) */

__device__ __forceinline__ bf16_t f2bf(float f) {
    uint32_t u = __builtin_bit_cast(uint32_t, f);
    u += 0x7FFFu + ((u >> 16) & 1u);
    uint16_t h = (uint16_t)(u >> 16);
    return __builtin_bit_cast(bf16_t, h);
}

// ---------------- Kernel 1: LayerNorm + Q/K bf16 prep ----------------
// one wave (64 lanes) per row of 512; 4 rows per 256-thread block
__global__ __launch_bounds__(256) void ln_prep(
    const float* __restrict__ x, const float* __restrict__ w, const float* __restrict__ bia,
    const float* __restrict__ qd, const float* __restrict__ kd,
    float* __restrict__ xn, bf16_t* __restrict__ qb, bf16_t* __restrict__ kb)
{
    int row  = (int)((blockIdx.x * blockDim.x + threadIdx.x) >> 6);
    int lane = threadIdx.x & 63;
    size_t base = (size_t)row * D_DIM + lane * 8;

    float xv[8];
    {
        float4 a0 = *(const float4*)(x + base);
        float4 a1 = *(const float4*)(x + base + 4);
        xv[0]=a0.x; xv[1]=a0.y; xv[2]=a0.z; xv[3]=a0.w;
        xv[4]=a1.x; xv[5]=a1.y; xv[6]=a1.z; xv[7]=a1.w;
    }
    float s = 0.f, s2 = 0.f;
    #pragma unroll
    for (int j = 0; j < 8; j++) { s += xv[j]; s2 += xv[j]*xv[j]; }
    #pragma unroll
    for (int m = 1; m < 64; m <<= 1) {
        s  += __shfl_xor(s,  m);
        s2 += __shfl_xor(s2, m);
    }
    float mu   = s  * (1.f/512.f);
    float var  = s2 * (1.f/512.f) - mu*mu;
    float rstd = rsqrtf(var + 1e-5f);

    int d = lane * 8;
    float wv[8], bv[8], qv[8], kv[8];
    {
        float4 t;
        t = *(const float4*)(w  + d);     wv[0]=t.x; wv[1]=t.y; wv[2]=t.z; wv[3]=t.w;
        t = *(const float4*)(w  + d + 4); wv[4]=t.x; wv[5]=t.y; wv[6]=t.z; wv[7]=t.w;
        t = *(const float4*)(bia+ d);     bv[0]=t.x; bv[1]=t.y; bv[2]=t.z; bv[3]=t.w;
        t = *(const float4*)(bia+ d + 4); bv[4]=t.x; bv[5]=t.y; bv[6]=t.z; bv[7]=t.w;
        t = *(const float4*)(qd + d);     qv[0]=t.x; qv[1]=t.y; qv[2]=t.z; qv[3]=t.w;
        t = *(const float4*)(qd + d + 4); qv[4]=t.x; qv[5]=t.y; qv[6]=t.z; qv[7]=t.w;
        t = *(const float4*)(kd + d);     kv[0]=t.x; kv[1]=t.y; kv[2]=t.z; kv[3]=t.w;
        t = *(const float4*)(kd + d + 4); kv[4]=t.x; kv[5]=t.y; kv[6]=t.z; kv[7]=t.w;
    }

    float xo[8];
    bf16x8 qo, ko;
    #pragma unroll
    for (int j = 0; j < 8; j++) {
        float v = (xv[j] - mu) * rstd * wv[j] + bv[j];
        xo[j] = v;
        qo[j] = f2bf(v * qv[j] * QK_SCALE);
        ko[j] = f2bf(v * kv[j]);
    }
    {
        float4 o0 = {xo[0],xo[1],xo[2],xo[3]};
        float4 o1 = {xo[4],xo[5],xo[6],xo[7]};
        *(float4*)(xn + base)     = o0;
        *(float4*)(xn + base + 4) = o1;
    }
    *(bf16x8*)(qb + base) = qo;
    *(bf16x8*)(kb + base) = ko;
}

// ---------------- Kernel 2: V^T prep (vT[b][d][n] bf16) ----------------
__global__ __launch_bounds__(256) void vT_prep(
    const float* __restrict__ xn, const float* __restrict__ vd, bf16_t* __restrict__ vT)
{
    __shared__ bf16_t tile[64][66];
    int b  = blockIdx.z;
    int n0 = blockIdx.x * 64;
    int d0 = blockIdx.y * 64;
    int t  = threadIdx.x;
    #pragma unroll
    for (int p = 0; p < 16; p++) {
        int idx = t + p*256;
        int nl = idx >> 6, dl = idx & 63;
        float v = xn[((size_t)b*N_DIM + n0 + nl)*D_DIM + d0 + dl] * vd[d0 + dl];
        tile[nl][dl] = f2bf(v);
    }
    __syncthreads();
    #pragma unroll
    for (int p = 0; p < 16; p++) {
        int idx = t + p*256;
        int dl = idx >> 6, nl = idx & 63;
        vT[((size_t)b*D_DIM + d0 + dl)*N_DIM + n0 + nl] = tile[nl][dl];
    }
}

// ---------------- Kernel 3: flash attention + residual ----------------
// grid (32, 8): (q-tile of 64 rows, batch). 512 threads = 8 waves.
// Wave w: QK^T role -> computes S rows [(w>>1)*16 .. +16), cols [(w&1)*32 .. +32)
//         PV   role -> owns O[64 rows][cols w*64 .. +64)
__global__ __launch_bounds__(512, 2) void attn(
    const bf16_t* __restrict__ qb, const bf16_t* __restrict__ kb,
    const bf16_t* __restrict__ vT, float* out)
{
    __shared__ __align__(16) bf16_t p_lds[64*64];   // swizzled P tile, rows of 128B
    __shared__ float part_m[2][64];
    __shared__ float part_l[2][64];
    __shared__ float m_lds[64], l_lds[64], alpha_lds[64], mnew_lds[64];

    const int b     = blockIdx.y;
    const int qbase = blockIdx.x * 64;
    const int tid   = threadIdx.x;
    const int wid   = tid >> 6;
    const int lane  = tid & 63;
    const int g     = lane >> 4;   // MFMA lane group
    const int li    = lane & 15;
    const int rf    = wid >> 1;    // q row-frag (0..3) for QK role
    const int ch    = wid & 1;     // key col half (0..1) for QK role

    if (tid < 64) { m_lds[tid] = -INFINITY; l_lds[tid] = 0.f; }

    // Q fragments in registers: rows rf*16+li, all 512 d (16 k-steps of 32)
    bf16x8 qf[16];
    {
        const bf16_t* qp = qb + ((size_t)(b*N_DIM + qbase + rf*16 + li)) * D_DIM + g*8;
        #pragma unroll
        for (int ks = 0; ks < 16; ks++)
            qf[ks] = *(const bf16x8*)(qp + ks*32);
    }

    f32x4 acc[4][4];
    const f32x4 zf = {0.f, 0.f, 0.f, 0.f};
    #pragma unroll
    for (int i = 0; i < 4; i++)
        #pragma unroll
        for (int j = 0; j < 4; j++) acc[i][j] = zf;

    __syncthreads();  // stats init visible

    const bf16_t* kb_b = kb + (size_t)b * N_DIM * D_DIM;
    const bf16_t* vT_b = vT + (size_t)b * D_DIM * N_DIM;

    for (int kt = 0; kt < 32; kt++) {
        const int kstart = kt * 64;

        // ---- QK^T: S strip [16 rows][32 cols] per wave ----
        f32x4 s0 = zf, s1 = zf;
        {
            const bf16_t* kp0 = kb_b + (size_t)(kstart + ch*32 + li) * D_DIM + g*8;
            const bf16_t* kp1 = kp0 + (size_t)16 * D_DIM;
            #pragma unroll
            for (int ks = 0; ks < 16; ks++) {
                bf16x8 k0 = *(const bf16x8*)(kp0 + ks*32);
                bf16x8 k1 = *(const bf16x8*)(kp1 + ks*32);
                s0 = __builtin_amdgcn_mfma_f32_16x16x32_bf16(qf[ks], k0, s0, 0, 0, 0);
                s1 = __builtin_amdgcn_mfma_f32_16x16x32_bf16(qf[ks], k1, s1, 0, 0, 0);
            }
        }

        // ---- partial row max over this wave's 32 cols ----
        #pragma unroll
        for (int r = 0; r < 4; r++) {
            float v = fmaxf(s0[r], s1[r]);
            v = fmaxf(v, __shfl_xor(v, 1));
            v = fmaxf(v, __shfl_xor(v, 2));
            v = fmaxf(v, __shfl_xor(v, 4));
            v = fmaxf(v, __shfl_xor(v, 8));
            if (li == 0) part_m[ch][rf*16 + g*4 + r] = v;
        }
        __syncthreads();

        if (tid < 64) {
            float mt = fmaxf(part_m[0][tid], part_m[1][tid]);
            float mo = m_lds[tid];
            float mn = fmaxf(mo, mt);
            mnew_lds[tid]  = mn;
            alpha_lds[tid] = __expf(mo - mn);
        }
        __syncthreads();

        // ---- P = exp(S - m_new): write swizzled LDS tile + partial row sums ----
        {
            #pragma unroll
            for (int r = 0; r < 4; r++) {
                int row = rf*16 + g*4 + r;
                float mn = mnew_lds[row];
                float p0 = __expf(s0[r] - mn);
                float p1 = __expf(s1[r] - mn);
                int col0 = ch*32 + li;
                uint32_t byte0 = (uint32_t)row*128 + (uint32_t)col0*2;
                uint32_t byte1 = byte0 + 32;
                byte0 ^= (uint32_t)(row & 7) << 4;
                byte1 ^= (uint32_t)(row & 7) << 4;
                *(bf16_t*)((char*)p_lds + byte0) = f2bf(p0);
                *(bf16_t*)((char*)p_lds + byte1) = f2bf(p1);
                float v = p0 + p1;
                v += __shfl_xor(v, 1);
                v += __shfl_xor(v, 2);
                v += __shfl_xor(v, 4);
                v += __shfl_xor(v, 8);
                if (li == 0) part_l[ch][row] = v;
            }
        }

        // ---- rescale O by alpha ----
        #pragma unroll
        for (int i = 0; i < 4; i++) {
            #pragma unroll
            for (int r = 0; r < 4; r++) {
                float al = alpha_lds[i*16 + g*4 + r];
                #pragma unroll
                for (int j = 0; j < 4; j++) acc[i][j][r] *= al;
            }
        }
        __syncthreads();   // p_lds + part_l ready

        if (tid < 64) {
            l_lds[tid] = l_lds[tid]*alpha_lds[tid] + part_l[0][tid] + part_l[1][tid];
            m_lds[tid] = mnew_lds[tid];
        }

        // ---- PV: O[64][wid*64..+64] += P * V ----
        {
            const bf16_t* vp = vT_b + (size_t)(wid*64 + li) * N_DIM + kstart + g*8;
            #pragma unroll
            for (int i = 0; i < 4; i++) {
                #pragma unroll
                for (int ks2 = 0; ks2 < 2; ks2++) {
                    int row = i*16 + li;
                    uint32_t byteA = (uint32_t)row*128 + (uint32_t)ks2*64 + (uint32_t)g*16;
                    byteA ^= (uint32_t)(row & 7) << 4;
                    bf16x8 af = *(const bf16x8*)((char*)p_lds + byteA);
                    #pragma unroll
                    for (int j = 0; j < 4; j++) {
                        bf16x8 bfr = *(const bf16x8*)(vp + (size_t)(j*16)*N_DIM + ks2*32);
                        acc[i][j] = __builtin_amdgcn_mfma_f32_16x16x32_bf16(af, bfr, acc[i][j], 0, 0, 0);
                    }
                }
            }
        }
        __syncthreads();   // p_lds/part_m safe for next tile; l_lds update done
    }

    // ---- epilogue: out = xn + O / l ----
    #pragma unroll
    for (int i = 0; i < 4; i++) {
        #pragma unroll
        for (int r = 0; r < 4; r++) {
            int row = i*16 + g*4 + r;
            float linv = 1.f / l_lds[row];
            size_t base = ((size_t)(b*N_DIM) + qbase + row) * D_DIM + wid*64 + li;
            #pragma unroll
            for (int j = 0; j < 4; j++) {
                size_t idx = base + (size_t)(j*16);
                out[idx] = out[idx] + acc[i][j][r] * linv;
            }
        }
    }
}

extern "C" void kernel_launch(void* const* d_in, const int* in_sizes, int n_in,
                              void* d_out, int out_size, void* d_ws, size_t ws_size,
                              hipStream_t stream)
{
    const float* x  = (const float*)d_in[0];
    const float* lw = (const float*)d_in[1];
    const float* lb = (const float*)d_in[2];
    const float* qd = (const float*)d_in[3];
    const float* kd = (const float*)d_in[4];
    const float* vd = (const float*)d_in[5];
    float* out = (float*)d_out;

    const size_t BYTES_BF = (size_t)B_DIM * N_DIM * D_DIM * 2;  // 16 MiB each
    char* ws = (char*)d_ws;
    bf16_t* qb = (bf16_t*)(ws);
    bf16_t* kb = (bf16_t*)(ws + BYTES_BF);
    bf16_t* vT = (bf16_t*)(ws + 2*BYTES_BF);

    // 16384 rows, 1 wave each, 4 rows per block
    ln_prep<<<4096, 256, 0, stream>>>(x, lw, lb, qd, kd, out, qb, kb);
    // transpose xn*v_diag -> vT[b][d][n]
    vT_prep<<<dim3(32, 8, 8), 256, 0, stream>>>(out, vd, vT);
    // flash attention + residual
    attn<<<dim3(32, 8), 512, 0, stream>>>(qb, kb, vT, out);
}

// Round 2
// 267.772 us; speedup vs baseline: 1.5427x; 1.5427x over previous
//
#include <hip/hip_runtime.h>
#include <hip/hip_bf16.h>
#include <stdint.h>
#include <math.h>

typedef __bf16 bf16_t;
typedef bf16_t bf16x8 __attribute__((ext_vector_type(8)));
typedef float f32x4 __attribute__((ext_vector_type(4)));

#define B_DIM 8
#define N_DIM 2048
#define D_DIM 512
#define QK_SCALE 0.04419417382415922f  /* 1/sqrt(512) */

// attn LDS layout (bytes)
#define KOFF 0          // K dbuf: 2 x 32768  ([32 k][512 d] bf16)
#define VOFF 65536      // V dbuf: 2 x 32768  ([512 d][32 k] bf16)
#define POFF 131072     // P tile: 8192       ([128 q][32 k] bf16)
#define AOFF 139264     // alpha: 128 f32
#define FOFF 139776     // flags: 8 int
#define SMEM_TOTAL 139840

__device__ __forceinline__ bf16_t f2bf(float f) {
    uint32_t u = __builtin_bit_cast(uint32_t, f);
    u += 0x7FFFu + ((u >> 16) & 1u);
    uint16_t h = (uint16_t)(u >> 16);
    return __builtin_bit_cast(bf16_t, h);
}

// ---------------- Kernel 1: LayerNorm + Q/K bf16 prep ----------------
__global__ __launch_bounds__(256) void ln_prep(
    const float* __restrict__ x, const float* __restrict__ w, const float* __restrict__ bia,
    const float* __restrict__ qd, const float* __restrict__ kd,
    float* __restrict__ xn, bf16_t* __restrict__ qb, bf16_t* __restrict__ kb)
{
    int row  = (int)((blockIdx.x * blockDim.x + threadIdx.x) >> 6);
    int lane = threadIdx.x & 63;
    size_t base = (size_t)row * D_DIM + lane * 8;

    float xv[8];
    {
        float4 a0 = *(const float4*)(x + base);
        float4 a1 = *(const float4*)(x + base + 4);
        xv[0]=a0.x; xv[1]=a0.y; xv[2]=a0.z; xv[3]=a0.w;
        xv[4]=a1.x; xv[5]=a1.y; xv[6]=a1.z; xv[7]=a1.w;
    }
    float s = 0.f, s2 = 0.f;
    #pragma unroll
    for (int j = 0; j < 8; j++) { s += xv[j]; s2 += xv[j]*xv[j]; }
    #pragma unroll
    for (int m = 1; m < 64; m <<= 1) {
        s  += __shfl_xor(s,  m);
        s2 += __shfl_xor(s2, m);
    }
    float mu   = s  * (1.f/512.f);
    float var  = s2 * (1.f/512.f) - mu*mu;
    float rstd = rsqrtf(var + 1e-5f);

    int d = lane * 8;
    float wv[8], bv[8], qv[8], kv[8];
    {
        float4 t;
        t = *(const float4*)(w  + d);     wv[0]=t.x; wv[1]=t.y; wv[2]=t.z; wv[3]=t.w;
        t = *(const float4*)(w  + d + 4); wv[4]=t.x; wv[5]=t.y; wv[6]=t.z; wv[7]=t.w;
        t = *(const float4*)(bia+ d);     bv[0]=t.x; bv[1]=t.y; bv[2]=t.z; bv[3]=t.w;
        t = *(const float4*)(bia+ d + 4); bv[4]=t.x; bv[5]=t.y; bv[6]=t.z; bv[7]=t.w;
        t = *(const float4*)(qd + d);     qv[0]=t.x; qv[1]=t.y; qv[2]=t.z; qv[3]=t.w;
        t = *(const float4*)(qd + d + 4); qv[4]=t.x; qv[5]=t.y; qv[6]=t.z; qv[7]=t.w;
        t = *(const float4*)(kd + d);     kv[0]=t.x; kv[1]=t.y; kv[2]=t.z; kv[3]=t.w;
        t = *(const float4*)(kd + d + 4); kv[4]=t.x; kv[5]=t.y; kv[6]=t.z; kv[7]=t.w;
    }

    float xo[8];
    bf16x8 qo, ko;
    #pragma unroll
    for (int j = 0; j < 8; j++) {
        float v = (xv[j] - mu) * rstd * wv[j] + bv[j];
        xo[j] = v;
        qo[j] = f2bf(v * qv[j] * QK_SCALE);
        ko[j] = f2bf(v * kv[j]);
    }
    {
        float4 o0 = {xo[0],xo[1],xo[2],xo[3]};
        float4 o1 = {xo[4],xo[5],xo[6],xo[7]};
        *(float4*)(xn + base)     = o0;
        *(float4*)(xn + base + 4) = o1;
    }
    *(bf16x8*)(qb + base) = qo;
    *(bf16x8*)(kb + base) = ko;
}

// ---------------- Kernel 2: V^T prep (vT[b][d][n] bf16) ----------------
__global__ __launch_bounds__(256) void vT_prep(
    const float* __restrict__ xn, const float* __restrict__ vd, bf16_t* __restrict__ vT)
{
    __shared__ bf16_t tile[64][66];
    int b  = blockIdx.z;
    int n0 = blockIdx.x * 64;
    int d0 = blockIdx.y * 64;
    int t  = threadIdx.x;
    #pragma unroll
    for (int p = 0; p < 16; p++) {
        int idx = t + p*256;
        int nl = idx >> 6, dl = idx & 63;
        float v = xn[((size_t)b*N_DIM + n0 + nl)*D_DIM + d0 + dl] * vd[d0 + dl];
        tile[nl][dl] = f2bf(v);
    }
    __syncthreads();
    #pragma unroll
    for (int p = 0; p < 16; p++) {
        int idx = t + p*256;
        int dl = idx >> 6, nl = idx & 63;
        vT[((size_t)b*D_DIM + d0 + dl)*N_DIM + n0 + nl] = tile[nl][dl];
    }
}

// ---------------- Kernel 3: flash attention (split-KV) ----------------
// grid 256: XCD-swizzled (batch, split, qtile). 512 thr = 8 waves.
// Wave w: owns q-rows [w*16, w*16+16) for QK+softmax (lane-local stats),
//         owns d-cols [w*64, w*64+64) x all 128 q-rows for O.
// KVBLK=32, K/V double-buffered LDS (global_load_lds), 2 raw barriers/iter.
__global__ __launch_bounds__(512, 2) void attn2(
    const bf16_t* __restrict__ qb, const bf16_t* __restrict__ kb,
    const bf16_t* __restrict__ vT, bf16_t* __restrict__ opart, float2* __restrict__ stats)
{
    extern __shared__ char smem[];
    float* alp = (float*)(smem + AOFF);
    int*   flg = (int*)(smem + FOFF);
    char*  Pb  = smem + POFF;

    // XCD-coherent mapping: group g=(b,s) -> 16 blocks on XCD g%8
    const int bid = blockIdx.x;
    const int xcd = bid & 7, jj = bid >> 3;
    const int grp = xcd + 8*(jj >> 4);
    const int qt  = jj & 15;
    const int b   = grp >> 1;
    const int s   = grp & 1;
    const int q0  = qt * 128;
    const int n0base = s * 1024;

    const int tid  = threadIdx.x;
    const int wid  = tid >> 6;
    const int lane = tid & 63;
    const int g    = lane >> 4;
    const int li   = lane & 15;

    const bf16_t* kb_b = kb + (size_t)b * N_DIM * D_DIM;
    const bf16_t* vT_b = vT + (size_t)b * D_DIM * N_DIM;

    // Q fragments: rows q0 + wid*16 + li, all 512 d (16 ksteps of 32)
    bf16x8 qf[16];
    {
        const bf16_t* qp = qb + ((size_t)(b*N_DIM + q0 + wid*16 + li)) * D_DIM + g*8;
        #pragma unroll
        for (int ks = 0; ks < 16; ks++)
            qf[ks] = *(const bf16x8*)(qp + ks*32);
    }

    f32x4 acc[8][4];
    const f32x4 zf = {0.f, 0.f, 0.f, 0.f};
    #pragma unroll
    for (int m = 0; m < 8; m++)
        #pragma unroll
        for (int j = 0; j < 4; j++) acc[m][j] = zf;

    float m_r[4] = {-INFINITY, -INFINITY, -INFINITY, -INFINITY};
    float l_r[4] = {0.f, 0.f, 0.f, 0.f};

    // staging lambda: K tile [32][512] (16B slots ^ row&7), V tile [512][32] (slots ^ d&3)
    const int Lk = lane ^ wid;                     // row&7 == wid for all K sweeps
    const int dl4 = lane >> 2;
    const int Lv = (lane & 3) ^ (dl4 & 3);
    auto stage = [&](int bufsel, int t) {
        const int kstart = n0base + t*32;
        char* kdst = smem + KOFF + bufsel*32768;
        char* vdst = smem + VOFF + bufsel*32768;
        #pragma unroll
        for (int v = 0; v < 4; v++) {
            int row = v*8 + wid;
            const bf16_t* src = kb_b + (size_t)(kstart + row)*D_DIM + Lk*8;
            __builtin_amdgcn_global_load_lds((const void*)src, (void*)(kdst + v*8192 + wid*1024), 16, 0, 0);
        }
        #pragma unroll
        for (int v = 0; v < 4; v++) {
            int d = v*128 + wid*16 + dl4;
            const bf16_t* src = vT_b + (size_t)d*N_DIM + kstart + Lv*8;
            __builtin_amdgcn_global_load_lds((const void*)src, (void*)(vdst + v*8192 + wid*1024), 16, 0, 0);
        }
    };

    // prologue: stage tile 0, drain, barrier
    stage(0, 0);
    asm volatile("s_waitcnt vmcnt(0) lgkmcnt(0)" ::: "memory");
    __builtin_amdgcn_s_barrier();

    const int swk = li & 7;
    #pragma unroll 2
    for (int t = 0; t < 32; ++t) {
        const int bufsel = t & 1;
        if (t < 31) stage(bufsel ^ 1, t + 1);      // prefetch next (in flight until bar2)

        // ---- QK^T: S[16 rows][32 k] per wave, from LDS K ----
        const char* Kb = smem + KOFF + bufsel*32768;
        const char* krow0 = Kb + li*1024;
        const char* krow1 = Kb + (16 + li)*1024;
        f32x4 sA = zf, sB = zf;
        #pragma unroll
        for (int ks = 0; ks < 16; ks++) {
            int phys = ((ks << 2) + g) ^ swk;
            bf16x8 k0 = *(const bf16x8*)(krow0 + phys*16);
            bf16x8 k1 = *(const bf16x8*)(krow1 + phys*16);
            sA = __builtin_amdgcn_mfma_f32_16x16x32_bf16(qf[ks], k0, sA, 0, 0, 0);
            sB = __builtin_amdgcn_mfma_f32_16x16x32_bf16(qf[ks], k1, sB, 0, 0, 0);
        }

        // ---- lane-local online softmax (rows g*4+r of this wave's mtile) ----
        float rm[4];
        #pragma unroll
        for (int r = 0; r < 4; r++) {
            float v = fmaxf(sA[r], sB[r]);
            v = fmaxf(v, __shfl_xor(v, 1));
            v = fmaxf(v, __shfl_xor(v, 2));
            v = fmaxf(v, __shfl_xor(v, 4));
            v = fmaxf(v, __shfl_xor(v, 8));
            rm[r] = v;
        }
        bool need = (rm[0] > m_r[0]) | (rm[1] > m_r[1]) | (rm[2] > m_r[2]) | (rm[3] > m_r[3]);
        int resc = __any(need);

        float al[4];
        #pragma unroll
        for (int r = 0; r < 4; r++) {
            float mn = fmaxf(m_r[r], rm[r]);
            al[r] = __expf(m_r[r] - mn);
            float p0 = __expf(sA[r] - mn);
            float p1 = __expf(sB[r] - mn);
            m_r[r] = mn;
            int q = (wid << 4) + (g << 2) + r;
            char* prow = Pb + q*64 + ((li & 7) << 1);
            *(bf16_t*)(prow + ((((li >> 3)    ) ^ r) << 4)) = f2bf(p0);
            *(bf16_t*)(prow + (((2 + (li >> 3)) ^ r) << 4)) = f2bf(p1);
            float rs = p0 + p1;
            rs += __shfl_xor(rs, 1);
            rs += __shfl_xor(rs, 2);
            rs += __shfl_xor(rs, 4);
            rs += __shfl_xor(rs, 8);
            l_r[r] = l_r[r]*al[r] + rs;
        }
        if (resc && li == 0) {
            #pragma unroll
            for (int r = 0; r < 4; r++) alp[(wid << 4) + (g << 2) + r] = al[r];
        }
        if (lane == 0) flg[wid] = resc;

        asm volatile("s_waitcnt lgkmcnt(0)" ::: "memory");   // P/alpha visible (prefetch stays in flight)
        __builtin_amdgcn_s_barrier();                        // bar1

        // ---- conditional rescale (exact T13: only mtiles whose max grew) ----
        #pragma unroll
        for (int m = 0; m < 8; m++) {
            if (flg[m]) {
                f32x4 a4 = *(const f32x4*)(alp + (m << 4) + (g << 2));
                #pragma unroll
                for (int j = 0; j < 4; j++)
                    #pragma unroll
                    for (int r = 0; r < 4; r++) acc[m][j][r] *= a4[r];
            }
        }

        // ---- PV: O[128][w*64..+64] += P * V, from LDS ----
        const char* Vb = smem + VOFF + bufsel*32768;
        bf16x8 vfr[4];
        #pragma unroll
        for (int j = 0; j < 4; j++) {
            int dcol = (wid << 6) + (j << 4) + li;
            vfr[j] = *(const bf16x8*)(Vb + dcol*64 + ((g ^ (li & 3)) << 4));
        }
        #pragma unroll
        for (int m = 0; m < 8; m++) {
            bf16x8 pa = *(const bf16x8*)(Pb + (m*16 + li)*64 + ((g ^ (li & 3)) << 4));
            #pragma unroll
            for (int j = 0; j < 4; j++)
                acc[m][j] = __builtin_amdgcn_mfma_f32_16x16x32_bf16(pa, vfr[j], acc[m][j], 0, 0, 0);
        }

        asm volatile("s_waitcnt vmcnt(0) lgkmcnt(0)" ::: "memory");  // drain prefetch + all LDS reads
        __builtin_amdgcn_s_barrier();                                // bar2
    }

    // ---- epilogue: unnormalized O (bf16) + per-row (m,l) ----
    bf16_t* op = opart + ((size_t)((s*8 + b)*N_DIM) + q0) * D_DIM;
    #pragma unroll
    for (int m = 0; m < 8; m++)
        #pragma unroll
        for (int j = 0; j < 4; j++)
            #pragma unroll
            for (int r = 0; r < 4; r++) {
                int qq = m*16 + (g << 2) + r;
                int dd = (wid << 6) + (j << 4) + li;
                op[(size_t)qq*D_DIM + dd] = f2bf(acc[m][j][r]);
            }
    if (li == 0) {
        float2* st = stats + (size_t)(s*8 + b)*N_DIM + q0;
        #pragma unroll
        for (int r = 0; r < 4; r++) {
            float2 ml; ml.x = m_r[r]; ml.y = l_r[r];
            st[(wid << 4) + (g << 2) + r] = ml;
        }
    }
}

// ---------------- Kernel 4: merge splits + residual ----------------
__global__ __launch_bounds__(256) void merge2(
    const bf16_t* __restrict__ opart, const float2* __restrict__ stats, float* __restrict__ out)
{
    int row  = (int)((blockIdx.x * blockDim.x + threadIdx.x) >> 6);  // b*2048+n
    int lane = threadIdx.x & 63;
    float2 s0 = stats[row];
    float2 s1 = stats[(size_t)16384 + row];
    float M  = fmaxf(s0.x, s1.x);
    float w0 = __expf(s0.x - M), w1 = __expf(s1.x - M);
    float rden = 1.f / (s0.y*w0 + s1.y*w1);
    size_t base = (size_t)row * D_DIM + lane*8;
    bf16x8 a = *(const bf16x8*)(opart + base);
    bf16x8 c = *(const bf16x8*)(opart + (size_t)16384*D_DIM + base);
    float4 x0 = *(const float4*)(out + base);
    float4 x1 = *(const float4*)(out + base + 4);
    float o[8];
    #pragma unroll
    for (int j = 0; j < 8; j++) o[j] = ((float)a[j]*w0 + (float)c[j]*w1) * rden;
    float4 r0 = {x0.x + o[0], x0.y + o[1], x0.z + o[2], x0.w + o[3]};
    float4 r1 = {x1.x + o[4], x1.y + o[5], x1.z + o[6], x1.w + o[7]};
    *(float4*)(out + base)     = r0;
    *(float4*)(out + base + 4) = r1;
}

extern "C" void kernel_launch(void* const* d_in, const int* in_sizes, int n_in,
                              void* d_out, int out_size, void* d_ws, size_t ws_size,
                              hipStream_t stream)
{
    const float* x  = (const float*)d_in[0];
    const float* lw = (const float*)d_in[1];
    const float* lb = (const float*)d_in[2];
    const float* qd = (const float*)d_in[3];
    const float* kd = (const float*)d_in[4];
    const float* vd = (const float*)d_in[5];
    float* out = (float*)d_out;

    // ws layout: qb 16MB | kb 16MB | vT 16MB | opart 32MB | stats 256KB  (80.3 MB)
    const size_t MB = 1024u*1024u;
    char* ws = (char*)d_ws;
    bf16_t* qbuf  = (bf16_t*)(ws);
    bf16_t* kbuf  = (bf16_t*)(ws + 16*MB);
    bf16_t* vTb   = (bf16_t*)(ws + 32*MB);
    bf16_t* opart = (bf16_t*)(ws + 48*MB);
    float2* stats = (float2*)(ws + 80*MB);

    hipFuncSetAttribute((const void*)attn2, hipFuncAttributeMaxDynamicSharedMemorySize, SMEM_TOTAL);

    ln_prep<<<4096, 256, 0, stream>>>(x, lw, lb, qd, kd, out, qbuf, kbuf);
    vT_prep<<<dim3(32, 8, 8), 256, 0, stream>>>(out, vd, vTb);
    attn2<<<256, 512, SMEM_TOTAL, stream>>>(qbuf, kbuf, vTb, opart, stats);
    merge2<<<4096, 256, 0, stream>>>(opart, stats, out);
}

// Round 3
// 205.772 us; speedup vs baseline: 2.0075x; 1.3013x over previous
//
#include <hip/hip_runtime.h>
#include <hip/hip_bf16.h>
#include <stdint.h>
#include <math.h>

typedef __bf16 bf16_t;
typedef bf16_t bf16x8 __attribute__((ext_vector_type(8)));
typedef bf16_t bf16x4 __attribute__((ext_vector_type(4)));
typedef float f32x4 __attribute__((ext_vector_type(4)));

#define B_DIM 8
#define N_DIM 2048
#define D_DIM 512
#define QK_SCALE 0.04419417382415922f  /* 1/sqrt(512) */

// attn LDS layout (bytes)
#define KOFF 0           // K dbuf: 2 x 32768  ([32 k][512 d] bf16, 16B-slot swizzled by row&7)
#define POFF 65536       // P: [128 q][32 k] bf16 = 8192 (16B-slot swizzled by q&3)
#define AOFF 73728       // alpha: 128 f32
#define FOFF 74240       // flags: 8 int
#define SMEM_TOTAL 74304

__device__ __forceinline__ bf16_t f2bf(float f) {
    uint32_t u = __builtin_bit_cast(uint32_t, f);
    u += 0x7FFFu + ((u >> 16) & 1u);
    uint16_t h = (uint16_t)(u >> 16);
    return __builtin_bit_cast(bf16_t, h);
}

__device__ __forceinline__ bf16x8 gload16(const bf16_t* p) {
    bf16x8 r;
    asm volatile("global_load_dwordx4 %0, %1, off" : "=v"(r) : "v"(p) : "memory");
    return r;
}

// ---------------- Kernel 1: LayerNorm + Q/K bf16 prep ----------------
__global__ __launch_bounds__(256) void ln_prep(
    const float* __restrict__ x, const float* __restrict__ w, const float* __restrict__ bia,
    const float* __restrict__ qd, const float* __restrict__ kd,
    float* __restrict__ xn, bf16_t* __restrict__ qb, bf16_t* __restrict__ kb)
{
    int row  = (int)((blockIdx.x * blockDim.x + threadIdx.x) >> 6);
    int lane = threadIdx.x & 63;
    size_t base = (size_t)row * D_DIM + lane * 8;

    float xv[8];
    {
        float4 a0 = *(const float4*)(x + base);
        float4 a1 = *(const float4*)(x + base + 4);
        xv[0]=a0.x; xv[1]=a0.y; xv[2]=a0.z; xv[3]=a0.w;
        xv[4]=a1.x; xv[5]=a1.y; xv[6]=a1.z; xv[7]=a1.w;
    }
    float s = 0.f, s2 = 0.f;
    #pragma unroll
    for (int j = 0; j < 8; j++) { s += xv[j]; s2 += xv[j]*xv[j]; }
    #pragma unroll
    for (int m = 1; m < 64; m <<= 1) {
        s  += __shfl_xor(s,  m);
        s2 += __shfl_xor(s2, m);
    }
    float mu   = s  * (1.f/512.f);
    float var  = s2 * (1.f/512.f) - mu*mu;
    float rstd = rsqrtf(var + 1e-5f);

    int d = lane * 8;
    float wv[8], bv[8], qv[8], kv[8];
    {
        float4 t;
        t = *(const float4*)(w  + d);     wv[0]=t.x; wv[1]=t.y; wv[2]=t.z; wv[3]=t.w;
        t = *(const float4*)(w  + d + 4); wv[4]=t.x; wv[5]=t.y; wv[6]=t.z; wv[7]=t.w;
        t = *(const float4*)(bia+ d);     bv[0]=t.x; bv[1]=t.y; bv[2]=t.z; bv[3]=t.w;
        t = *(const float4*)(bia+ d + 4); bv[4]=t.x; bv[5]=t.y; bv[6]=t.z; bv[7]=t.w;
        t = *(const float4*)(qd + d);     qv[0]=t.x; qv[1]=t.y; qv[2]=t.z; qv[3]=t.w;
        t = *(const float4*)(qd + d + 4); qv[4]=t.x; qv[5]=t.y; qv[6]=t.z; qv[7]=t.w;
        t = *(const float4*)(kd + d);     kv[0]=t.x; kv[1]=t.y; kv[2]=t.z; kv[3]=t.w;
        t = *(const float4*)(kd + d + 4); kv[4]=t.x; kv[5]=t.y; kv[6]=t.z; kv[7]=t.w;
    }

    float xo[8];
    bf16x8 qo, ko;
    #pragma unroll
    for (int j = 0; j < 8; j++) {
        float v = (xv[j] - mu) * rstd * wv[j] + bv[j];
        xo[j] = v;
        qo[j] = f2bf(v * qv[j] * QK_SCALE);
        ko[j] = f2bf(v * kv[j]);
    }
    {
        float4 o0 = {xo[0],xo[1],xo[2],xo[3]};
        float4 o1 = {xo[4],xo[5],xo[6],xo[7]};
        *(float4*)(xn + base)     = o0;
        *(float4*)(xn + base + 4) = o1;
    }
    *(bf16x8*)(qb + base) = qo;
    *(bf16x8*)(kb + base) = ko;
}

// ---------------- Kernel 2: V^T prep (vT[b][d][n] bf16) ----------------
__global__ __launch_bounds__(256) void vT_prep(
    const float* __restrict__ xn, const float* __restrict__ vd, bf16_t* __restrict__ vT)
{
    __shared__ bf16_t tile[64][66];
    int b  = blockIdx.z;
    int n0 = blockIdx.x * 64;
    int d0 = blockIdx.y * 64;
    int t  = threadIdx.x;
    #pragma unroll
    for (int p = 0; p < 16; p++) {
        int idx = t + p*256;
        int nl = idx >> 6, dl = idx & 63;
        float v = xn[((size_t)b*N_DIM + n0 + nl)*D_DIM + d0 + dl] * vd[d0 + dl];
        tile[nl][dl] = f2bf(v);
    }
    __syncthreads();
    #pragma unroll
    for (int p = 0; p < 16; p++) {
        int idx = t + p*256;
        int dl = idx >> 6, nl = idx & 63;
        vT[((size_t)b*D_DIM + d0 + dl)*N_DIM + n0 + nl] = tile[nl][dl];
    }
}

// ---------------- Kernel 3: flash attention (split-KV, swapped QK^T) ----------------
// grid 256: XCD-grouped (batch,split) x 16 qtiles. 512 thr = 8 waves.
// Wave w: QK+softmax for q-rows [w*16,w*16+16), lane-local stats (q = li after swap).
//         PV owns d-cols [w*64, w*64+64) x all 128 q-rows.
// KVBLK=32. K double-buffered LDS via global_load_lds; V direct global->reg.
__global__ __launch_bounds__(512, 2) void attn3(
    const bf16_t* __restrict__ qb, const bf16_t* __restrict__ kb,
    const bf16_t* __restrict__ vT, bf16_t* __restrict__ opart, float2* __restrict__ stats)
{
    extern __shared__ char smem[];
    float* alp = (float*)(smem + AOFF);
    int*   flg = (int*)(smem + FOFF);
    char*  Pb  = smem + POFF;

    const int bid = blockIdx.x;
    const int xcd = bid & 7, jj = bid >> 3;
    const int grp = xcd + 8*(jj >> 4);   // (b,s) group -> one XCD
    const int qt  = jj & 15;
    const int b   = grp >> 1;
    const int s   = grp & 1;
    const int q0  = qt * 128;
    const int n0base = s * 1024;

    const int tid  = threadIdx.x;
    const int wid  = tid >> 6;
    const int lane = tid & 63;
    const int g    = lane >> 4;
    const int li   = lane & 15;

    const bf16_t* kb_b = kb + (size_t)b * N_DIM * D_DIM;
    const bf16_t* vT_b = vT + (size_t)b * D_DIM * N_DIM;

    // Q fragments (loop-invariant): rows q0 + wid*16 + li over all 512 d
    bf16x8 qf[16];
    {
        const bf16_t* qp = qb + ((size_t)(b*N_DIM + q0 + wid*16 + li)) * D_DIM + g*8;
        #pragma unroll
        for (int ks = 0; ks < 16; ks++)
            qf[ks] = *(const bf16x8*)(qp + ks*32);
    }

    f32x4 acc[8][4];
    const f32x4 zf = {0.f, 0.f, 0.f, 0.f};
    #pragma unroll
    for (int m = 0; m < 8; m++)
        #pragma unroll
        for (int j = 0; j < 4; j++) acc[m][j] = zf;

    float m_r = -INFINITY, l_r = 0.f;

    // K staging: tile [32 k][512 d], 4 sweeps of 8 rows; 16B-slot swizzle: slot = chunk ^ (row&7)
    const int Lk = (lane ^ wid) * 8;
    auto stageK = [&](int buf, int t) {
        const int kstart = n0base + t*32;
        char* kdst = smem + KOFF + buf*32768;
        #pragma unroll
        for (int v = 0; v < 4; v++) {
            int row = v*8 + wid;
            const bf16_t* src = kb_b + (size_t)(kstart + row)*D_DIM + Lk;
            __builtin_amdgcn_global_load_lds((const void*)src, (void*)(kdst + row*1024), 16, 0, 0);
        }
    };

    stageK(0, 0);
    asm volatile("s_waitcnt vmcnt(0)" ::: "memory");
    __builtin_amdgcn_s_barrier();

    const int sw = li & 7;
    const int psw = (li & 3) << 4;

    for (int t = 0; t < 32; ++t) {
        const int buf = t & 1;
        const int kstart = n0base + t*32;

        // ---- V fragments for tile t (oldest in vmcnt queue) ----
        bf16x8 vfr[4];
        #pragma unroll
        for (int j = 0; j < 4; j++) {
            const bf16_t* vp = vT_b + (size_t)(wid*64 + j*16 + li)*N_DIM + kstart + g*8;
            vfr[j] = gload16(vp);
        }
        // ---- prefetch next K tile (stays in flight until bar2) ----
        stageK(buf ^ 1, (t < 31) ? t + 1 : 0);

        // ---- swapped QK^T: S^T[32 k][16 q], lane holds q=li, k = {tile*16+g*4+r} ----
        const char* kr0 = smem + KOFF + buf*32768 + li*1024;
        const char* kr1 = kr0 + 16*1024;
        f32x4 s0 = zf, s1 = zf;
        #pragma unroll
        for (int ks = 0; ks < 16; ks++) {
            int phys = (((ks << 2) + g) ^ sw) << 4;
            bf16x8 k0 = *(const bf16x8*)(kr0 + phys);
            bf16x8 k1 = *(const bf16x8*)(kr1 + phys);
            s0 = __builtin_amdgcn_mfma_f32_16x16x32_bf16(k0, qf[ks], s0, 0, 0, 0);
            s1 = __builtin_amdgcn_mfma_f32_16x16x32_bf16(k1, qf[ks], s1, 0, 0, 0);
        }

        // ---- lane-local online softmax (defer-max THR=8) ----
        float pmax = fmaxf(fmaxf(fmaxf(s0[0], s0[1]), fmaxf(s0[2], s0[3])),
                           fmaxf(fmaxf(s1[0], s1[1]), fmaxf(s1[2], s1[3])));
        pmax = fmaxf(pmax, __shfl_xor(pmax, 16));
        pmax = fmaxf(pmax, __shfl_xor(pmax, 32));
        int resc = __any(pmax > m_r + 8.f);
        float al = 1.f;
        if (resc) {
            float mn = fmaxf(m_r, pmax);
            al = __expf(m_r - mn);
            m_r = mn;
            if (g == 0) alp[wid*16 + li] = al;
        }
        if (lane == 0) flg[wid] = resc;

        float p0[4], p1[4];
        #pragma unroll
        for (int r = 0; r < 4; r++) {
            p0[r] = __expf(s0[r] - m_r);
            p1[r] = __expf(s1[r] - m_r);
        }
        float rs = (p0[0]+p0[1]) + (p0[2]+p0[3]) + ((p1[0]+p1[1]) + (p1[2]+p1[3]));
        rs += __shfl_xor(rs, 16);
        rs += __shfl_xor(rs, 32);
        l_r = l_r * al + rs;

        // ---- P -> LDS (q = wid*16+li): two b64 writes, slot-swizzled by q&3 ----
        {
            bf16x4 w0 = {f2bf(p0[0]), f2bf(p0[1]), f2bf(p0[2]), f2bf(p0[3])};
            bf16x4 w1 = {f2bf(p1[0]), f2bf(p1[1]), f2bf(p1[2]), f2bf(p1[3])};
            char* prow = Pb + (wid*16 + li)*64;
            *(bf16x4*)(prow + ((g*8)      ^ psw)) = w0;
            *(bf16x4*)(prow + ((32 + g*8) ^ psw)) = w1;
        }

        asm volatile("s_waitcnt lgkmcnt(0)" ::: "memory");   // publish P/alp/flg
        __builtin_amdgcn_s_barrier();                        // bar1 (K-prefetch stays in flight)

        // ---- rare rescale (T13) ----
        #pragma unroll
        for (int m = 0; m < 8; m++) {
            if (flg[m]) {
                f32x4 a4 = *(const f32x4*)(alp + m*16 + g*4);
                #pragma unroll
                for (int j = 0; j < 4; j++)
                    #pragma unroll
                    for (int r = 0; r < 4; r++) acc[m][j][r] *= a4[r];
            }
        }

        // ---- PV: drain only V frags (vmcnt(4) leaves 4 K-stage loads in flight) ----
        asm volatile("s_waitcnt vmcnt(4)" ::: "memory");
        __builtin_amdgcn_sched_barrier(0);
        #pragma unroll
        for (int m = 0; m < 8; m++) {
            const char* prow = Pb + (m*16 + li)*64;
            bf16x8 pa = *(const bf16x8*)(prow + ((g << 4) ^ psw));
            #pragma unroll
            for (int j = 0; j < 4; j++)
                acc[m][j] = __builtin_amdgcn_mfma_f32_16x16x32_bf16(pa, vfr[j], acc[m][j], 0, 0, 0);
        }

        asm volatile("s_waitcnt vmcnt(0) lgkmcnt(0)" ::: "memory");  // K(t+1) arrived; LDS reads done
        __builtin_amdgcn_s_barrier();                                // bar2
    }

    // ---- epilogue: unnormalized O (bf16) + per-row (m,l) ----
    bf16_t* op = opart + ((size_t)((s*8 + b)*N_DIM) + q0) * D_DIM;
    #pragma unroll
    for (int m = 0; m < 8; m++)
        #pragma unroll
        for (int j = 0; j < 4; j++)
            #pragma unroll
            for (int r = 0; r < 4; r++) {
                int qq = m*16 + g*4 + r;
                int dd = wid*64 + j*16 + li;
                op[(size_t)qq*D_DIM + dd] = f2bf(acc[m][j][r]);
            }
    if (lane < 16) {
        float2 ml; ml.x = m_r; ml.y = l_r;
        stats[(size_t)(s*8 + b)*N_DIM + q0 + wid*16 + lane] = ml;
    }
}

// ---------------- Kernel 4: merge splits + residual ----------------
__global__ __launch_bounds__(256) void merge2(
    const bf16_t* __restrict__ opart, const float2* __restrict__ stats, float* __restrict__ out)
{
    int row  = (int)((blockIdx.x * blockDim.x + threadIdx.x) >> 6);  // b*2048+n
    int lane = threadIdx.x & 63;
    float2 s0 = stats[row];
    float2 s1 = stats[(size_t)16384 + row];
    float M  = fmaxf(s0.x, s1.x);
    float w0 = __expf(s0.x - M), w1 = __expf(s1.x - M);
    float rden = 1.f / (s0.y*w0 + s1.y*w1);
    size_t base = (size_t)row * D_DIM + lane*8;
    bf16x8 a = *(const bf16x8*)(opart + base);
    bf16x8 c = *(const bf16x8*)(opart + (size_t)16384*D_DIM + base);
    float4 x0 = *(const float4*)(out + base);
    float4 x1 = *(const float4*)(out + base + 4);
    float o[8];
    #pragma unroll
    for (int j = 0; j < 8; j++) o[j] = ((float)a[j]*w0 + (float)c[j]*w1) * rden;
    float4 r0 = {x0.x + o[0], x0.y + o[1], x0.z + o[2], x0.w + o[3]};
    float4 r1 = {x1.x + o[4], x1.y + o[5], x1.z + o[6], x1.w + o[7]};
    *(float4*)(out + base)     = r0;
    *(float4*)(out + base + 4) = r1;
}

extern "C" void kernel_launch(void* const* d_in, const int* in_sizes, int n_in,
                              void* d_out, int out_size, void* d_ws, size_t ws_size,
                              hipStream_t stream)
{
    const float* x  = (const float*)d_in[0];
    const float* lw = (const float*)d_in[1];
    const float* lb = (const float*)d_in[2];
    const float* qd = (const float*)d_in[3];
    const float* kd = (const float*)d_in[4];
    const float* vd = (const float*)d_in[5];
    float* out = (float*)d_out;

    // ws layout: qb 16MB | kb 16MB | vT 16MB | opart 32MB | stats 256KB
    const size_t MB = 1024u*1024u;
    char* ws = (char*)d_ws;
    bf16_t* qbuf  = (bf16_t*)(ws);
    bf16_t* kbuf  = (bf16_t*)(ws + 16*MB);
    bf16_t* vTb   = (bf16_t*)(ws + 32*MB);
    bf16_t* opart = (bf16_t*)(ws + 48*MB);
    float2* stats = (float2*)(ws + 80*MB);

    hipFuncSetAttribute((const void*)attn3, hipFuncAttributeMaxDynamicSharedMemorySize, SMEM_TOTAL);

    ln_prep<<<4096, 256, 0, stream>>>(x, lw, lb, qd, kd, out, qbuf, kbuf);
    vT_prep<<<dim3(32, 8, 8), 256, 0, stream>>>(out, vd, vTb);
    attn3<<<256, 512, SMEM_TOTAL, stream>>>(qbuf, kbuf, vTb, opart, stats);
    merge2<<<4096, 256, 0, stream>>>(opart, stats, out);
}

// Round 4
// 192.648 us; speedup vs baseline: 2.1442x; 1.0681x over previous
//
#include <hip/hip_runtime.h>
#include <hip/hip_bf16.h>
#include <stdint.h>
#include <math.h>

typedef __bf16 bf16_t;
typedef bf16_t bf16x8 __attribute__((ext_vector_type(8)));
typedef bf16_t bf16x4 __attribute__((ext_vector_type(4)));
typedef float f32x4 __attribute__((ext_vector_type(4)));

#define B_DIM 8
#define N_DIM 2048
#define D_DIM 512
#define QK_SCALE 0.04419417382415922f  /* 1/sqrt(512) */

// attn LDS layout (bytes): K ring x3, P, alpha, flags
#define KOFF 0            // 3 x 32768 ([32 k][512 d] bf16, 16B-slot ^ (row&7))
#define POFF 98304        // P: [128 q][32 k] bf16 = 8192, 16B-slot ^ ((q>>1)&3)
#define AOFF 106496       // alpha: 128 f32
#define FOFF 107008       // flags: 8 int
#define SMEM_TOTAL 107040

__device__ __forceinline__ bf16_t f2bf(float f) {
    uint32_t u = __builtin_bit_cast(uint32_t, f);
    u += 0x7FFFu + ((u >> 16) & 1u);
    uint16_t h = (uint16_t)(u >> 16);
    return __builtin_bit_cast(bf16_t, h);
}

__device__ __forceinline__ bf16x8 gload16(const bf16_t* p) {
    bf16x8 r;
    asm volatile("global_load_dwordx4 %0, %1, off" : "=v"(r) : "v"(p) : "memory");
    return r;
}

// ---------------- Kernel 1: LayerNorm + Q/K bf16 prep ----------------
__global__ __launch_bounds__(256) void ln_prep(
    const float* __restrict__ x, const float* __restrict__ w, const float* __restrict__ bia,
    const float* __restrict__ qd, const float* __restrict__ kd,
    float* __restrict__ xn, bf16_t* __restrict__ qb, bf16_t* __restrict__ kb)
{
    int row  = (int)((blockIdx.x * blockDim.x + threadIdx.x) >> 6);
    int lane = threadIdx.x & 63;
    size_t base = (size_t)row * D_DIM + lane * 8;

    float xv[8];
    {
        float4 a0 = *(const float4*)(x + base);
        float4 a1 = *(const float4*)(x + base + 4);
        xv[0]=a0.x; xv[1]=a0.y; xv[2]=a0.z; xv[3]=a0.w;
        xv[4]=a1.x; xv[5]=a1.y; xv[6]=a1.z; xv[7]=a1.w;
    }
    float s = 0.f, s2 = 0.f;
    #pragma unroll
    for (int j = 0; j < 8; j++) { s += xv[j]; s2 += xv[j]*xv[j]; }
    #pragma unroll
    for (int m = 1; m < 64; m <<= 1) {
        s  += __shfl_xor(s,  m);
        s2 += __shfl_xor(s2, m);
    }
    float mu   = s  * (1.f/512.f);
    float var  = s2 * (1.f/512.f) - mu*mu;
    float rstd = rsqrtf(var + 1e-5f);

    int d = lane * 8;
    float wv[8], bv[8], qv[8], kv[8];
    {
        float4 t;
        t = *(const float4*)(w  + d);     wv[0]=t.x; wv[1]=t.y; wv[2]=t.z; wv[3]=t.w;
        t = *(const float4*)(w  + d + 4); wv[4]=t.x; wv[5]=t.y; wv[6]=t.z; wv[7]=t.w;
        t = *(const float4*)(bia+ d);     bv[0]=t.x; bv[1]=t.y; bv[2]=t.z; bv[3]=t.w;
        t = *(const float4*)(bia+ d + 4); bv[4]=t.x; bv[5]=t.y; bv[6]=t.z; bv[7]=t.w;
        t = *(const float4*)(qd + d);     qv[0]=t.x; qv[1]=t.y; qv[2]=t.z; qv[3]=t.w;
        t = *(const float4*)(qd + d + 4); qv[4]=t.x; qv[5]=t.y; qv[6]=t.z; qv[7]=t.w;
        t = *(const float4*)(kd + d);     kv[0]=t.x; kv[1]=t.y; kv[2]=t.z; kv[3]=t.w;
        t = *(const float4*)(kd + d + 4); kv[4]=t.x; kv[5]=t.y; kv[6]=t.z; kv[7]=t.w;
    }

    float xo[8];
    bf16x8 qo, ko;
    #pragma unroll
    for (int j = 0; j < 8; j++) {
        float v = (xv[j] - mu) * rstd * wv[j] + bv[j];
        xo[j] = v;
        qo[j] = f2bf(v * qv[j] * QK_SCALE);
        ko[j] = f2bf(v * kv[j]);
    }
    {
        float4 o0 = {xo[0],xo[1],xo[2],xo[3]};
        float4 o1 = {xo[4],xo[5],xo[6],xo[7]};
        *(float4*)(xn + base)     = o0;
        *(float4*)(xn + base + 4) = o1;
    }
    *(bf16x8*)(qb + base) = qo;
    *(bf16x8*)(kb + base) = ko;
}

// ---------------- Kernel 2: V^T prep (vT[b][d][n] bf16) ----------------
__global__ __launch_bounds__(256) void vT_prep(
    const float* __restrict__ xn, const float* __restrict__ vd, bf16_t* __restrict__ vT)
{
    __shared__ bf16_t tile[64][66];
    int b  = blockIdx.z;
    int n0 = blockIdx.x * 64;
    int d0 = blockIdx.y * 64;
    int t  = threadIdx.x;
    #pragma unroll
    for (int p = 0; p < 16; p++) {
        int idx = t + p*256;
        int nl = idx >> 6, dl = idx & 63;
        float v = xn[((size_t)b*N_DIM + n0 + nl)*D_DIM + d0 + dl] * vd[d0 + dl];
        tile[nl][dl] = f2bf(v);
    }
    __syncthreads();
    #pragma unroll
    for (int p = 0; p < 16; p++) {
        int idx = t + p*256;
        int dl = idx >> 6, nl = idx & 63;
        vT[((size_t)b*D_DIM + d0 + dl)*N_DIM + n0 + nl] = tile[nl][dl];
    }
}

// ---------------- Kernel 3: flash attention (split-KV, swapped QK^T) ----------------
// grid 256: XCD-grouped (batch,split) x 16 qtiles. 512 thr = 8 waves.
// K ring-buffer depth 3, counted vmcnt (never drains to 0 in the loop).
__global__ __launch_bounds__(512, 2) void attn4(
    const bf16_t* __restrict__ qb, const bf16_t* __restrict__ kb,
    const bf16_t* __restrict__ vT, bf16_t* __restrict__ opart, float2* __restrict__ stats)
{
    extern __shared__ char smem[];
    float* alp = (float*)(smem + AOFF);
    int*   flg = (int*)(smem + FOFF);
    char*  Pb  = smem + POFF;

    const int bid = blockIdx.x;
    const int xcd = bid & 7, jj = bid >> 3;
    const int grp = xcd + 8*(jj >> 4);   // (b,s) group -> one XCD
    const int qt  = jj & 15;
    const int b   = grp >> 1;
    const int s   = grp & 1;
    const int q0  = qt * 128;
    const int n0base = s * 1024;

    const int tid  = threadIdx.x;
    const int wid  = tid >> 6;
    const int lane = tid & 63;
    const int g    = lane >> 4;
    const int li   = lane & 15;

    const bf16_t* kb_b = kb + (size_t)b * N_DIM * D_DIM;
    const bf16_t* vT_b = vT + (size_t)b * D_DIM * N_DIM;

    // Q fragments (loop-invariant): rows q0 + wid*16 + li over all 512 d
    bf16x8 qf[16];
    {
        const bf16_t* qp = qb + ((size_t)(b*N_DIM + q0 + wid*16 + li)) * D_DIM + g*8;
        #pragma unroll
        for (int ks = 0; ks < 16; ks++)
            qf[ks] = *(const bf16x8*)(qp + ks*32);
    }

    f32x4 acc[8][4];
    const f32x4 zf = {0.f, 0.f, 0.f, 0.f};
    #pragma unroll
    for (int m = 0; m < 8; m++)
        #pragma unroll
        for (int j = 0; j < 4; j++) acc[m][j] = zf;

    float m_r = -INFINITY, l_r = 0.f;

    // K staging: tile [32 k][512 d], 4 sweeps of 8 rows; 16B-slot swizzle: slot = chunk ^ (row&7)
    const int Lk = (lane ^ wid) * 8;
    auto stageK = [&](int buf, int t) {
        const int kstart = n0base + t*32;
        char* kdst = smem + KOFF + buf*32768;
        #pragma unroll
        for (int v = 0; v < 4; v++) {
            int row = v*8 + wid;
            const bf16_t* src = kb_b + (size_t)(kstart + row)*D_DIM + Lk;
            __builtin_amdgcn_global_load_lds((const void*)src, (void*)(kdst + row*1024), 16, 0, 0);
        }
    };

    // prologue: stage K(0), K(1); wait K(0) only (K(1) stays in flight)
    stageK(0, 0);
    stageK(1, 1);
    asm volatile("s_waitcnt vmcnt(4)" ::: "memory");
    __builtin_amdgcn_s_barrier();

    const int sw  = li & 7;           // K-read salt
    const int ps  = (li >> 1) & 3;    // P salt: conflict-free within 8-lane groups

    for (int t = 0; t < 32; ++t) {
        const int buf = t % 3;
        const int nxt = (t + 2 >= 32) ? (t + 2 - 32) : (t + 2);   // ring slot index math
        const int nbuf = (t + 2) % 3;
        const int kstart = n0base + t*32;

        // ---- V fragments for tile t (issued first: oldest after K(t+1)) ----
        bf16x8 vfr[4];
        #pragma unroll
        for (int j = 0; j < 4; j++) {
            const bf16_t* vp = vT_b + (size_t)(wid*64 + j*16 + li)*N_DIM + kstart + g*8;
            vfr[j] = gload16(vp);
        }
        __builtin_amdgcn_sched_barrier(0);   // pin V-before-K issue order (vmcnt accounting)
        // ---- stage K(t+2) into ring (stays in flight across both barriers) ----
        stageK(nbuf, (t + 2 < 32) ? t + 2 : 0);
        __builtin_amdgcn_sched_barrier(0);
        (void)nxt;

        // ---- swapped QK^T: S^T[32 k][16 q]; lane: q=li, k = g*4+r (+16) ----
        const char* kr0 = smem + KOFF + buf*32768 + li*1024;
        const char* kr1 = kr0 + 16*1024;
        f32x4 s0 = zf, s1 = zf;
        __builtin_amdgcn_s_setprio(1);
        #pragma unroll
        for (int ks = 0; ks < 16; ks++) {
            int phys = (((ks << 2) + g) ^ sw) << 4;
            bf16x8 k0 = *(const bf16x8*)(kr0 + phys);
            bf16x8 k1 = *(const bf16x8*)(kr1 + phys);
            s0 = __builtin_amdgcn_mfma_f32_16x16x32_bf16(k0, qf[ks], s0, 0, 0, 0);
            s1 = __builtin_amdgcn_mfma_f32_16x16x32_bf16(k1, qf[ks], s1, 0, 0, 0);
        }
        __builtin_amdgcn_s_setprio(0);

        // ---- lane-local online softmax (defer-max THR=8) ----
        float pmax = fmaxf(fmaxf(fmaxf(s0[0], s0[1]), fmaxf(s0[2], s0[3])),
                           fmaxf(fmaxf(s1[0], s1[1]), fmaxf(s1[2], s1[3])));
        pmax = fmaxf(pmax, __shfl_xor(pmax, 16));
        pmax = fmaxf(pmax, __shfl_xor(pmax, 32));
        int resc = __any(pmax > m_r + 8.f);
        float al = 1.f;
        if (resc) {
            float mn = fmaxf(m_r, pmax);
            al = __expf(m_r - mn);
            m_r = mn;
            if (g == 0) alp[wid*16 + li] = al;
        }
        if (lane == 0) flg[wid] = resc;

        float p0[4], p1[4];
        #pragma unroll
        for (int r = 0; r < 4; r++) {
            p0[r] = __expf(s0[r] - m_r);
            p1[r] = __expf(s1[r] - m_r);
        }
        float rs = (p0[0]+p0[1]) + (p0[2]+p0[3]) + ((p1[0]+p1[1]) + (p1[2]+p1[3]));
        rs += __shfl_xor(rs, 16);
        rs += __shfl_xor(rs, 32);
        l_r = l_r * al + rs;

        // ---- P -> LDS: row q = wid*16+li; two b64 writes, slot = logical ^ ps ----
        {
            bf16x4 w0 = {f2bf(p0[0]), f2bf(p0[1]), f2bf(p0[2]), f2bf(p0[3])};
            bf16x4 w1 = {f2bf(p1[0]), f2bf(p1[1]), f2bf(p1[2]), f2bf(p1[3])};
            char* prow = Pb + (wid*16 + li)*64;
            int h = (g & 1) * 8;
            *(bf16x4*)(prow + ((((g >> 1)    ) ^ ps) << 4) + h) = w0;
            *(bf16x4*)(prow + (((2 + (g >> 1)) ^ ps) << 4) + h) = w1;
        }

        asm volatile("s_waitcnt lgkmcnt(0)" ::: "memory");   // publish P/alp/flg
        __builtin_amdgcn_s_barrier();                        // bar1

        // ---- rare rescale (T13) ----
        #pragma unroll
        for (int m = 0; m < 8; m++) {
            if (flg[m]) {
                f32x4 a4 = *(const f32x4*)(alp + m*16 + g*4);
                #pragma unroll
                for (int j = 0; j < 4; j++)
                    #pragma unroll
                    for (int r = 0; r < 4; r++) acc[m][j][r] *= a4[r];
            }
        }

        // ---- drain V + K(t+1); K(t+2) stays in flight (counted vmcnt) ----
        asm volatile("s_waitcnt vmcnt(4)" ::: "memory");
        __builtin_amdgcn_sched_barrier(0);

        // ---- PV: O[128][w*64..+64] += P * V ----
        __builtin_amdgcn_s_setprio(1);
        #pragma unroll
        for (int m = 0; m < 8; m++) {
            const char* prow = Pb + (m*16 + li)*64;
            bf16x8 pa = *(const bf16x8*)(prow + ((g ^ ps) << 4));
            #pragma unroll
            for (int j = 0; j < 4; j++)
                acc[m][j] = __builtin_amdgcn_mfma_f32_16x16x32_bf16(pa, vfr[j], acc[m][j], 0, 0, 0);
        }
        __builtin_amdgcn_s_setprio(0);

        asm volatile("s_waitcnt lgkmcnt(0)" ::: "memory");   // P reads retired
        __builtin_amdgcn_s_barrier();                        // bar2
    }

    // ---- epilogue: unnormalized O (bf16) + per-row (m,l) ----
    bf16_t* op = opart + ((size_t)((s*8 + b)*N_DIM) + q0) * D_DIM;
    #pragma unroll
    for (int m = 0; m < 8; m++)
        #pragma unroll
        for (int j = 0; j < 4; j++)
            #pragma unroll
            for (int r = 0; r < 4; r++) {
                int qq = m*16 + g*4 + r;
                int dd = wid*64 + j*16 + li;
                op[(size_t)qq*D_DIM + dd] = f2bf(acc[m][j][r]);
            }
    if (lane < 16) {
        float2 ml; ml.x = m_r; ml.y = l_r;
        stats[(size_t)(s*8 + b)*N_DIM + q0 + wid*16 + lane] = ml;
    }
}

// ---------------- Kernel 4: merge splits + residual ----------------
__global__ __launch_bounds__(256) void merge2(
    const bf16_t* __restrict__ opart, const float2* __restrict__ stats, float* __restrict__ out)
{
    int row  = (int)((blockIdx.x * blockDim.x + threadIdx.x) >> 6);  // b*2048+n
    int lane = threadIdx.x & 63;
    float2 s0 = stats[row];
    float2 s1 = stats[(size_t)16384 + row];
    float M  = fmaxf(s0.x, s1.x);
    float w0 = __expf(s0.x - M), w1 = __expf(s1.x - M);
    float rden = 1.f / (s0.y*w0 + s1.y*w1);
    size_t base = (size_t)row * D_DIM + lane*8;
    bf16x8 a = *(const bf16x8*)(opart + base);
    bf16x8 c = *(const bf16x8*)(opart + (size_t)16384*D_DIM + base);
    float4 x0 = *(const float4*)(out + base);
    float4 x1 = *(const float4*)(out + base + 4);
    float o[8];
    #pragma unroll
    for (int j = 0; j < 8; j++) o[j] = ((float)a[j]*w0 + (float)c[j]*w1) * rden;
    float4 r0 = {x0.x + o[0], x0.y + o[1], x0.z + o[2], x0.w + o[3]};
    float4 r1 = {x1.x + o[4], x1.y + o[5], x1.z + o[6], x1.w + o[7]};
    *(float4*)(out + base)     = r0;
    *(float4*)(out + base + 4) = r1;
}

extern "C" void kernel_launch(void* const* d_in, const int* in_sizes, int n_in,
                              void* d_out, int out_size, void* d_ws, size_t ws_size,
                              hipStream_t stream)
{
    const float* x  = (const float*)d_in[0];
    const float* lw = (const float*)d_in[1];
    const float* lb = (const float*)d_in[2];
    const float* qd = (const float*)d_in[3];
    const float* kd = (const float*)d_in[4];
    const float* vd = (const float*)d_in[5];
    float* out = (float*)d_out;

    // ws layout: qb 16MB | kb 16MB | vT 16MB | opart 32MB | stats 256KB
    const size_t MB = 1024u*1024u;
    char* ws = (char*)d_ws;
    bf16_t* qbuf  = (bf16_t*)(ws);
    bf16_t* kbuf  = (bf16_t*)(ws + 16*MB);
    bf16_t* vTb   = (bf16_t*)(ws + 32*MB);
    bf16_t* opart = (bf16_t*)(ws + 48*MB);
    float2* stats = (float2*)(ws + 80*MB);

    hipFuncSetAttribute((const void*)attn4, hipFuncAttributeMaxDynamicSharedMemorySize, SMEM_TOTAL);

    ln_prep<<<4096, 256, 0, stream>>>(x, lw, lb, qd, kd, out, qbuf, kbuf);
    vT_prep<<<dim3(32, 8, 8), 256, 0, stream>>>(out, vd, vTb);
    attn4<<<256, 512, SMEM_TOTAL, stream>>>(qbuf, kbuf, vTb, opart, stats);
    merge2<<<4096, 256, 0, stream>>>(opart, stats, out);
}

// Round 5
// 160.639 us; speedup vs baseline: 2.5715x; 1.1993x over previous
//
#include <hip/hip_runtime.h>
#include <hip/hip_bf16.h>
#include <stdint.h>
#include <math.h>

typedef __bf16 bf16_t;
typedef bf16_t bf16x8 __attribute__((ext_vector_type(8)));
typedef bf16_t bf16x4 __attribute__((ext_vector_type(4)));
typedef float f32x4 __attribute__((ext_vector_type(4)));

#define B_DIM 8
#define N_DIM 2048
#define D_DIM 512
#define QK_SCALE 0.04419417382415922f  /* 1/sqrt(512) */
#define M_SHIFT 4.0f                   /* static softmax shift; safe: |S|<=22.6 < 88 */

// attn LDS layout (bytes): K ring x3, P dbuf x2
#define KOFF 0            // 3 x 32768 ([32 k][512 d] bf16, 16B-slot ^ (row&7))
#define POFF 98304        // 2 x 8192  ([128 q][32 k] bf16, 16B-slot ^ ((q>>1)&3))
#define SMEM_TOTAL 114688

__device__ __forceinline__ bf16_t f2bf(float f) {
    uint32_t u = __builtin_bit_cast(uint32_t, f);
    u += 0x7FFFu + ((u >> 16) & 1u);
    uint16_t h = (uint16_t)(u >> 16);
    return __builtin_bit_cast(bf16_t, h);
}

__device__ __forceinline__ bf16x8 gload16(const bf16_t* p) {
    bf16x8 r;
    asm volatile("global_load_dwordx4 %0, %1, off" : "=v"(r) : "v"(p) : "memory");
    return r;
}

// ---------------- Kernel 1: LayerNorm + Q/K bf16 prep ----------------
__global__ __launch_bounds__(256) void ln_prep(
    const float* __restrict__ x, const float* __restrict__ w, const float* __restrict__ bia,
    const float* __restrict__ qd, const float* __restrict__ kd,
    float* __restrict__ xn, bf16_t* __restrict__ qb, bf16_t* __restrict__ kb)
{
    int row  = (int)((blockIdx.x * blockDim.x + threadIdx.x) >> 6);
    int lane = threadIdx.x & 63;
    size_t base = (size_t)row * D_DIM + lane * 8;

    float xv[8];
    {
        float4 a0 = *(const float4*)(x + base);
        float4 a1 = *(const float4*)(x + base + 4);
        xv[0]=a0.x; xv[1]=a0.y; xv[2]=a0.z; xv[3]=a0.w;
        xv[4]=a1.x; xv[5]=a1.y; xv[6]=a1.z; xv[7]=a1.w;
    }
    float s = 0.f, s2 = 0.f;
    #pragma unroll
    for (int j = 0; j < 8; j++) { s += xv[j]; s2 += xv[j]*xv[j]; }
    #pragma unroll
    for (int m = 1; m < 64; m <<= 1) {
        s  += __shfl_xor(s,  m);
        s2 += __shfl_xor(s2, m);
    }
    float mu   = s  * (1.f/512.f);
    float var  = s2 * (1.f/512.f) - mu*mu;
    float rstd = rsqrtf(var + 1e-5f);

    int d = lane * 8;
    float wv[8], bv[8], qv[8], kv[8];
    {
        float4 t;
        t = *(const float4*)(w  + d);     wv[0]=t.x; wv[1]=t.y; wv[2]=t.z; wv[3]=t.w;
        t = *(const float4*)(w  + d + 4); wv[4]=t.x; wv[5]=t.y; wv[6]=t.z; wv[7]=t.w;
        t = *(const float4*)(bia+ d);     bv[0]=t.x; bv[1]=t.y; bv[2]=t.z; bv[3]=t.w;
        t = *(const float4*)(bia+ d + 4); bv[4]=t.x; bv[5]=t.y; bv[6]=t.z; bv[7]=t.w;
        t = *(const float4*)(qd + d);     qv[0]=t.x; qv[1]=t.y; qv[2]=t.z; qv[3]=t.w;
        t = *(const float4*)(qd + d + 4); qv[4]=t.x; qv[5]=t.y; qv[6]=t.z; qv[7]=t.w;
        t = *(const float4*)(kd + d);     kv[0]=t.x; kv[1]=t.y; kv[2]=t.z; kv[3]=t.w;
        t = *(const float4*)(kd + d + 4); kv[4]=t.x; kv[5]=t.y; kv[6]=t.z; kv[7]=t.w;
    }

    float xo[8];
    bf16x8 qo, ko;
    #pragma unroll
    for (int j = 0; j < 8; j++) {
        float v = (xv[j] - mu) * rstd * wv[j] + bv[j];
        xo[j] = v;
        qo[j] = f2bf(v * qv[j] * QK_SCALE);
        ko[j] = f2bf(v * kv[j]);
    }
    {
        float4 o0 = {xo[0],xo[1],xo[2],xo[3]};
        float4 o1 = {xo[4],xo[5],xo[6],xo[7]};
        *(float4*)(xn + base)     = o0;
        *(float4*)(xn + base + 4) = o1;
    }
    *(bf16x8*)(qb + base) = qo;
    *(bf16x8*)(kb + base) = ko;
}

// ---------------- Kernel 2: V^T prep (vT[b][d][n] bf16) ----------------
__global__ __launch_bounds__(256) void vT_prep(
    const float* __restrict__ xn, const float* __restrict__ vd, bf16_t* __restrict__ vT)
{
    __shared__ bf16_t tile[64][66];
    int b  = blockIdx.z;
    int n0 = blockIdx.x * 64;
    int d0 = blockIdx.y * 64;
    int t  = threadIdx.x;
    #pragma unroll
    for (int p = 0; p < 16; p++) {
        int idx = t + p*256;
        int nl = idx >> 6, dl = idx & 63;
        float v = xn[((size_t)b*N_DIM + n0 + nl)*D_DIM + d0 + dl] * vd[d0 + dl];
        tile[nl][dl] = f2bf(v);
    }
    __syncthreads();
    #pragma unroll
    for (int p = 0; p < 16; p++) {
        int idx = t + p*256;
        int dl = idx >> 6, nl = idx & 63;
        vT[((size_t)b*D_DIM + d0 + dl)*N_DIM + n0 + nl] = tile[nl][dl];
    }
}

// ---------------- Kernel 3: flash attention (split-KV, swapped QK^T, static-m) ----------------
// grid 256: XCD-grouped (batch,split) x 16 qtiles. 512 thr = 8 waves.
// ONE barrier per iter: P double-buffered, K ring-3, counted vmcnt (never 0 in loop).
// Static softmax shift (LN bounds |S| <= sqrt(512)): no max tracking, no rescale,
// l accumulated per-lane and reduced once after the loop.
__global__ __launch_bounds__(512, 2) void attn5(
    const bf16_t* __restrict__ qb, const bf16_t* __restrict__ kb,
    const bf16_t* __restrict__ vT, bf16_t* __restrict__ opart, float* __restrict__ stats)
{
    extern __shared__ char smem[];
    char* Pb = smem + POFF;

    const int bid = blockIdx.x;
    const int xcd = bid & 7, jj = bid >> 3;
    const int grp = xcd + 8*(jj >> 4);   // (b,s) group -> one XCD
    const int qt  = jj & 15;
    const int b   = grp >> 1;
    const int s   = grp & 1;
    const int q0  = qt * 128;
    const int n0base = s * 1024;

    const int tid  = threadIdx.x;
    const int wid  = tid >> 6;
    const int lane = tid & 63;
    const int g    = lane >> 4;
    const int li   = lane & 15;

    const bf16_t* kb_b = kb + (size_t)b * N_DIM * D_DIM;
    const bf16_t* vT_b = vT + (size_t)b * D_DIM * N_DIM;

    // Q fragments (loop-invariant): rows q0 + wid*16 + li over all 512 d
    bf16x8 qf[16];
    {
        const bf16_t* qp = qb + ((size_t)(b*N_DIM + q0 + wid*16 + li)) * D_DIM + g*8;
        #pragma unroll
        for (int ks = 0; ks < 16; ks++)
            qf[ks] = *(const bf16x8*)(qp + ks*32);
    }

    f32x4 acc[8][4];
    const f32x4 zf = {0.f, 0.f, 0.f, 0.f};
    #pragma unroll
    for (int m = 0; m < 8; m++)
        #pragma unroll
        for (int j = 0; j < 4; j++) acc[m][j] = zf;

    float l_r = 0.f;   // per-lane partial; reduced after the loop

    // K staging: tile [32 k][512 d], 4 sweeps of 8 rows; 16B-slot swizzle: slot = chunk ^ (row&7)
    const int Lk = (lane ^ wid) * 8;
    auto stageK = [&](int buf, int t) {
        const int kstart = n0base + t*32;
        char* kdst = smem + KOFF + buf*32768;
        #pragma unroll
        for (int v = 0; v < 4; v++) {
            int row = v*8 + wid;
            const bf16_t* src = kb_b + (size_t)(kstart + row)*D_DIM + Lk;
            __builtin_amdgcn_global_load_lds((const void*)src, (void*)(kdst + row*1024), 16, 0, 0);
        }
    };

    // prologue: stage K(0), K(1); confirm K(0) (K(1) stays in flight)
    stageK(0, 0);
    stageK(1, 1);
    asm volatile("s_waitcnt vmcnt(4)" ::: "memory");
    __builtin_amdgcn_s_barrier();

    const int sw  = li & 7;           // K-read salt
    const int ps  = (li >> 1) & 3;    // P salt

    for (int t = 0; t < 32; ++t) {
        const int buf  = t % 3;
        const int nbuf = (t + 2) % 3;
        const int kstart = n0base + t*32;
        char* Pw = Pb + (t & 1) * 8192;

        // [A] V fragments for tile t (oldest after K(t+1))
        bf16x8 vfr[4];
        #pragma unroll
        for (int j = 0; j < 4; j++) {
            const bf16_t* vp = vT_b + (size_t)(wid*64 + j*16 + li)*N_DIM + kstart + g*8;
            vfr[j] = gload16(vp);
        }
        __builtin_amdgcn_sched_barrier(0);   // pin V-before-K issue order
        // [B] stage K(t+2) into ring (in flight across the barrier)
        stageK(nbuf, (t + 2 < 32) ? t + 2 : 0);
        __builtin_amdgcn_sched_barrier(0);

        // [C] swapped QK^T: S^T[32 k][16 q]; lane: q=li, k = g*4+r (+16)
        const char* kr0 = smem + KOFF + buf*32768 + li*1024;
        const char* kr1 = kr0 + 16*1024;
        f32x4 s0 = zf, s1 = zf;
        __builtin_amdgcn_s_setprio(1);
        #pragma unroll
        for (int ks = 0; ks < 16; ks++) {
            int phys = (((ks << 2) + g) ^ sw) << 4;
            bf16x8 k0 = *(const bf16x8*)(kr0 + phys);
            bf16x8 k1 = *(const bf16x8*)(kr1 + phys);
            s0 = __builtin_amdgcn_mfma_f32_16x16x32_bf16(k0, qf[ks], s0, 0, 0, 0);
            s1 = __builtin_amdgcn_mfma_f32_16x16x32_bf16(k1, qf[ks], s1, 0, 0, 0);
        }
        __builtin_amdgcn_s_setprio(0);

        // [D] static-shift softmax: fully lane-local
        float p0[4], p1[4];
        #pragma unroll
        for (int r = 0; r < 4; r++) {
            p0[r] = __expf(s0[r] - M_SHIFT);
            p1[r] = __expf(s1[r] - M_SHIFT);
        }
        l_r += ((p0[0]+p0[1]) + (p0[2]+p0[3])) + ((p1[0]+p1[1]) + (p1[2]+p1[3]));
        {
            bf16x4 w0 = {f2bf(p0[0]), f2bf(p0[1]), f2bf(p0[2]), f2bf(p0[3])};
            bf16x4 w1 = {f2bf(p1[0]), f2bf(p1[1]), f2bf(p1[2]), f2bf(p1[3])};
            char* prow = Pw + (wid*16 + li)*64;
            int h = (g & 1) * 8;
            *(bf16x4*)(prow + ((((g >> 1))     ^ ps) << 4) + h) = w0;
            *(bf16x4*)(prow + (((2 + (g >> 1)) ^ ps) << 4) + h) = w1;
        }

        // [E] confirm K(t+1) (for next-iter QK) + publish P; V(t), K(t+2) stay in flight
        asm volatile("s_waitcnt vmcnt(8) lgkmcnt(0)" ::: "memory");
        __builtin_amdgcn_s_barrier();

        // [F] retire V(t) only (K(t+2) still flying), then PV
        asm volatile("s_waitcnt vmcnt(4)" ::: "memory");
        __builtin_amdgcn_sched_barrier(0);
        __builtin_amdgcn_s_setprio(1);
        #pragma unroll
        for (int m = 0; m < 8; m++) {
            const char* prow = Pw + (m*16 + li)*64;
            bf16x8 pa = *(const bf16x8*)(prow + ((g ^ ps) << 4));
            #pragma unroll
            for (int j = 0; j < 4; j++)
                acc[m][j] = __builtin_amdgcn_mfma_f32_16x16x32_bf16(pa, vfr[j], acc[m][j], 0, 0, 0);
        }
        __builtin_amdgcn_s_setprio(0);
        // no second barrier: P is double-buffered; next write to this P buffer
        // happens only after the next [E] barrier (own reads drained by its lgkmcnt(0))
    }

    // ---- epilogue: reduce l across k-groups, store unnormalized O (bf16) + l ----
    l_r += __shfl_xor(l_r, 16);
    l_r += __shfl_xor(l_r, 32);

    bf16_t* op = opart + ((size_t)((s*8 + b)*N_DIM) + q0) * D_DIM;
    #pragma unroll
    for (int m = 0; m < 8; m++)
        #pragma unroll
        for (int j = 0; j < 4; j++)
            #pragma unroll
            for (int r = 0; r < 4; r++) {
                int qq = m*16 + g*4 + r;
                int dd = wid*64 + j*16 + li;
                op[(size_t)qq*D_DIM + dd] = f2bf(acc[m][j][r]);
            }
    if (lane < 16) {
        stats[(size_t)(s*8 + b)*N_DIM + q0 + wid*16 + lane] = l_r;
    }
}

// ---------------- Kernel 4: merge splits + residual (exact: same static shift) ----------------
__global__ __launch_bounds__(256) void merge2(
    const bf16_t* __restrict__ opart, const float* __restrict__ stats, float* __restrict__ out)
{
    int row  = (int)((blockIdx.x * blockDim.x + threadIdx.x) >> 6);  // b*2048+n
    int lane = threadIdx.x & 63;
    float l0 = stats[row];
    float l1 = stats[(size_t)16384 + row];
    float rden = 1.f / (l0 + l1);
    size_t base = (size_t)row * D_DIM + lane*8;
    bf16x8 a = *(const bf16x8*)(opart + base);
    bf16x8 c = *(const bf16x8*)(opart + (size_t)16384*D_DIM + base);
    float4 x0 = *(const float4*)(out + base);
    float4 x1 = *(const float4*)(out + base + 4);
    float o[8];
    #pragma unroll
    for (int j = 0; j < 8; j++) o[j] = ((float)a[j] + (float)c[j]) * rden;
    float4 r0 = {x0.x + o[0], x0.y + o[1], x0.z + o[2], x0.w + o[3]};
    float4 r1 = {x1.x + o[4], x1.y + o[5], x1.z + o[6], x1.w + o[7]};
    *(float4*)(out + base)     = r0;
    *(float4*)(out + base + 4) = r1;
}

extern "C" void kernel_launch(void* const* d_in, const int* in_sizes, int n_in,
                              void* d_out, int out_size, void* d_ws, size_t ws_size,
                              hipStream_t stream)
{
    const float* x  = (const float*)d_in[0];
    const float* lw = (const float*)d_in[1];
    const float* lb = (const float*)d_in[2];
    const float* qd = (const float*)d_in[3];
    const float* kd = (const float*)d_in[4];
    const float* vd = (const float*)d_in[5];
    float* out = (float*)d_out;

    // ws layout: qb 16MB | kb 16MB | vT 16MB | opart 32MB | stats 64KB
    const size_t MB = 1024u*1024u;
    char* ws = (char*)d_ws;
    bf16_t* qbuf  = (bf16_t*)(ws);
    bf16_t* kbuf  = (bf16_t*)(ws + 16*MB);
    bf16_t* vTb   = (bf16_t*)(ws + 32*MB);
    bf16_t* opart = (bf16_t*)(ws + 48*MB);
    float*  stats = (float*)(ws + 80*MB);

    hipFuncSetAttribute((const void*)attn5, hipFuncAttributeMaxDynamicSharedMemorySize, SMEM_TOTAL);

    ln_prep<<<4096, 256, 0, stream>>>(x, lw, lb, qd, kd, out, qbuf, kbuf);
    vT_prep<<<dim3(32, 8, 8), 256, 0, stream>>>(out, vd, vTb);
    attn5<<<256, 512, SMEM_TOTAL, stream>>>(qbuf, kbuf, vTb, opart, stats);
    merge2<<<4096, 256, 0, stream>>>(opart, stats, out);
}

// Round 6
// 129.605 us; speedup vs baseline: 3.1872x; 1.2394x over previous
//
#include <hip/hip_runtime.h>
#include <hip/hip_bf16.h>
#include <stdint.h>
#include <math.h>

typedef __bf16 bf16_t;
typedef bf16_t bf16x8 __attribute__((ext_vector_type(8)));
typedef float f32x4 __attribute__((ext_vector_type(4)));

#define B_DIM 8
#define N_DIM 2048
#define D_DIM 512
#define QK_SCALE 0.04419417382415922f  /* 1/sqrt(512) */
#define M_SHIFT 4.0f                   /* static softmax shift; safe: |S|<=22.6 */

// attn LDS layout (bytes): K dbuf x2, V dbuf x2
#define KOFF 0            // 2 x 32768 ([32 k][512 d] bf16, 16B-slot ^ (row&7))
#define VOFF 65536        // 2 x 32768 ([512 d][32 k] bf16, k pre-permuted, slot ^ ((d>>1)&3))
#define SMEM_TOTAL 131072

__device__ __forceinline__ bf16_t f2bf(float f) {
    uint32_t u = __builtin_bit_cast(uint32_t, f);
    u += 0x7FFFu + ((u >> 16) & 1u);
    uint16_t h = (uint16_t)(u >> 16);
    return __builtin_bit_cast(bf16_t, h);
}

// ---------------- Kernel 1: LayerNorm + Q/K bf16 prep ----------------
__global__ __launch_bounds__(256) void ln_prep(
    const float* __restrict__ x, const float* __restrict__ w, const float* __restrict__ bia,
    const float* __restrict__ qd, const float* __restrict__ kd,
    float* __restrict__ xn, bf16_t* __restrict__ qb, bf16_t* __restrict__ kb)
{
    int row  = (int)((blockIdx.x * blockDim.x + threadIdx.x) >> 6);
    int lane = threadIdx.x & 63;
    size_t base = (size_t)row * D_DIM + lane * 8;

    float xv[8];
    {
        float4 a0 = *(const float4*)(x + base);
        float4 a1 = *(const float4*)(x + base + 4);
        xv[0]=a0.x; xv[1]=a0.y; xv[2]=a0.z; xv[3]=a0.w;
        xv[4]=a1.x; xv[5]=a1.y; xv[6]=a1.z; xv[7]=a1.w;
    }
    float s = 0.f, s2 = 0.f;
    #pragma unroll
    for (int j = 0; j < 8; j++) { s += xv[j]; s2 += xv[j]*xv[j]; }
    #pragma unroll
    for (int m = 1; m < 64; m <<= 1) {
        s  += __shfl_xor(s,  m);
        s2 += __shfl_xor(s2, m);
    }
    float mu   = s  * (1.f/512.f);
    float var  = s2 * (1.f/512.f) - mu*mu;
    float rstd = rsqrtf(var + 1e-5f);

    int d = lane * 8;
    float wv[8], bv[8], qv[8], kv[8];
    {
        float4 t;
        t = *(const float4*)(w  + d);     wv[0]=t.x; wv[1]=t.y; wv[2]=t.z; wv[3]=t.w;
        t = *(const float4*)(w  + d + 4); wv[4]=t.x; wv[5]=t.y; wv[6]=t.z; wv[7]=t.w;
        t = *(const float4*)(bia+ d);     bv[0]=t.x; bv[1]=t.y; bv[2]=t.z; bv[3]=t.w;
        t = *(const float4*)(bia+ d + 4); bv[4]=t.x; bv[5]=t.y; bv[6]=t.z; bv[7]=t.w;
        t = *(const float4*)(qd + d);     qv[0]=t.x; qv[1]=t.y; qv[2]=t.z; qv[3]=t.w;
        t = *(const float4*)(qd + d + 4); qv[4]=t.x; qv[5]=t.y; qv[6]=t.z; qv[7]=t.w;
        t = *(const float4*)(kd + d);     kv[0]=t.x; kv[1]=t.y; kv[2]=t.z; kv[3]=t.w;
        t = *(const float4*)(kd + d + 4); kv[4]=t.x; kv[5]=t.y; kv[6]=t.z; kv[7]=t.w;
    }

    float xo[8];
    bf16x8 qo, ko;
    #pragma unroll
    for (int j = 0; j < 8; j++) {
        float v = (xv[j] - mu) * rstd * wv[j] + bv[j];
        xo[j] = v;
        qo[j] = f2bf(v * qv[j] * QK_SCALE);
        ko[j] = f2bf(v * kv[j]);
    }
    {
        float4 o0 = {xo[0],xo[1],xo[2],xo[3]};
        float4 o1 = {xo[4],xo[5],xo[6],xo[7]};
        *(float4*)(xn + base)     = o0;
        *(float4*)(xn + base + 4) = o1;
    }
    *(bf16x8*)(qb + base) = qo;
    *(bf16x8*)(kb + base) = ko;
}

// ---------------- Kernel 2: V^T prep, k-PERMUTED + bank-salted layout ----------------
// vT[b][d][kblk of 32]: 4 slots of 16B per 64B block. Physical slot sp holds
// logical g = sp ^ ((d>>1)&3); its 8 bf16 are k = kblk*32 + {4g..4g+3, 16+4g..16+4g+3}.
// This matches the PV A-frag (lane-local P order) so PV needs no P exchange at all.
__global__ __launch_bounds__(256) void vT_prep(
    const float* __restrict__ xn, const float* __restrict__ vd, bf16_t* __restrict__ vT)
{
    __shared__ bf16_t tile[64][66];
    int b  = blockIdx.z;
    int n0 = blockIdx.x * 64;   // k-range of this tile
    int d0 = blockIdx.y * 64;
    int t  = threadIdx.x;
    #pragma unroll
    for (int p = 0; p < 16; p++) {
        int idx = t + p*256;
        int nl = idx >> 6, dl = idx & 63;
        float v = xn[((size_t)b*N_DIM + n0 + nl)*D_DIM + d0 + dl] * vd[d0 + dl];
        tile[nl][dl] = f2bf(v);
    }
    __syncthreads();
    #pragma unroll
    for (int p = 0; p < 2; p++) {
        int idx = t + p*256;          // 0..511
        int sfull = idx & 7;          // 16B slot within 128B (2 kblks) of one d-row
        int dl  = idx >> 3;           // 0..63
        int kb  = sfull >> 2;
        int sp  = sfull & 3;
        int g   = sp ^ ((dl >> 1) & 3);
        bf16x8 o;
        #pragma unroll
        for (int e = 0; e < 4; e++) o[e]   = tile[kb*32 + 4*g + e][dl];
        #pragma unroll
        for (int e = 0; e < 4; e++) o[4+e] = tile[kb*32 + 16 + 4*g + e][dl];
        *(bf16x8*)(vT + ((size_t)(b*D_DIM + d0 + dl))*N_DIM + n0 + kb*32 + sp*8) = o;
    }
}

// ---------------- Kernel 3: flash attention (split-KV, swapped QK^T, P-in-reg) ----------------
// grid 256: XCD-grouped (batch,split) x 16 qtiles. 512 thr = 8 waves.
// Wave w owns q-rows [w*16, w*16+16) end-to-end: QK -> lane-local softmax ->
// P packed in-register as the PV A-frag (k-bijection) -> PV over all 512 d.
// K+V double-buffered LDS via global_load_lds; ONE barrier per iter (stage publish).
__global__ __launch_bounds__(512, 2) void attn6(
    const bf16_t* __restrict__ qb, const bf16_t* __restrict__ kb,
    const bf16_t* __restrict__ vT, bf16_t* __restrict__ opart, float* __restrict__ stats)
{
    extern __shared__ char smem[];

    const int bid = blockIdx.x;
    const int xcd = bid & 7, jj = bid >> 3;
    const int grp = xcd + 8*(jj >> 4);   // (b,s) group -> one XCD
    const int qt  = jj & 15;
    const int b   = grp >> 1;
    const int s   = grp & 1;
    const int q0  = qt * 128;
    const int n0base = s * 1024;

    const int tid  = threadIdx.x;
    const int wid  = tid >> 6;
    const int lane = tid & 63;
    const int g    = lane >> 4;
    const int li   = lane & 15;

    const bf16_t* kb_b = kb + (size_t)b * N_DIM * D_DIM;
    const bf16_t* vT_b = vT + (size_t)b * D_DIM * N_DIM;

    // Q fragments (loop-invariant): rows q0 + wid*16 + li over all 512 d
    bf16x8 qf[16];
    {
        const bf16_t* qp = qb + ((size_t)(b*N_DIM + q0 + wid*16 + li)) * D_DIM + g*8;
        #pragma unroll
        for (int ks = 0; ks < 16; ks++)
            qf[ks] = *(const bf16x8*)(qp + ks*32);
    }

    f32x4 acc[32];
    const f32x4 zf = {0.f, 0.f, 0.f, 0.f};
    #pragma unroll
    for (int j = 0; j < 32; j++) acc[j] = zf;

    float l_r = 0.f;   // per-lane partial; reduced once after the loop

    // K staging: [32 k][512 d], 16B-slot swizzle: slot = chunk ^ (row&7)
    const int Lk = (lane ^ wid) * 8;
    auto stageK = [&](int buf, int t) {
        const int kstart = n0base + t*32;
        char* kdst = smem + KOFF + buf*32768;
        #pragma unroll
        for (int v = 0; v < 4; v++) {
            int row = v*8 + wid;
            const bf16_t* src = kb_b + (size_t)(kstart + row)*D_DIM + Lk;
            __builtin_amdgcn_global_load_lds((const void*)src, (void*)(kdst + row*1024), 16, 0, 0);
        }
    };
    // V staging: [512 d][32 k] (64B rows, already permuted+salted in global) -> linear copy
    auto stageV = [&](int buf, int t) {
        const int kstart = n0base + t*32;
        char* vdst = smem + VOFF + buf*32768 + wid*4096;
        const int drow = wid*64 + (lane >> 2);
        const bf16_t* src0 = vT_b + (size_t)drow*N_DIM + kstart + (lane & 3)*8;
        #pragma unroll
        for (int v = 0; v < 4; v++) {
            __builtin_amdgcn_global_load_lds((const void*)(src0 + (size_t)(v*16)*N_DIM),
                                             (void*)(vdst + v*1024), 16, 0, 0);
        }
    };

    // prologue: stage tile 0, drain, barrier
    stageK(0, 0);
    stageV(0, 0);
    asm volatile("s_waitcnt vmcnt(0)" ::: "memory");
    __builtin_amdgcn_s_barrier();

    const int sw  = li & 7;                 // K-read salt
    const int vsw = (g ^ ((li >> 1) & 3)) << 4;  // V-read slot (lane-constant)

    #pragma unroll 1
    for (int t = 0; t < 32; ++t) {
        const int buf = t & 1;

        // [A] stage next tile (in flight across the whole body; confirmed at [D])
        if (t < 31) {
            stageK(buf ^ 1, t + 1);
            stageV(buf ^ 1, t + 1);
        }
        __builtin_amdgcn_sched_barrier(0);

        // [B] swapped QK^T: S^T[32 k][16 q]; lane: q=li, k = 4g+r (s0) / 16+4g+r (s1)
        const char* kr0 = smem + KOFF + buf*32768 + li*1024;
        const char* kr1 = kr0 + 16*1024;
        f32x4 s0 = zf, s1 = zf;
        __builtin_amdgcn_s_setprio(1);
        #pragma unroll
        for (int ks = 0; ks < 16; ks++) {
            int phys = (((ks << 2) + g) ^ sw) << 4;
            bf16x8 k0 = *(const bf16x8*)(kr0 + phys);
            bf16x8 k1 = *(const bf16x8*)(kr1 + phys);
            s0 = __builtin_amdgcn_mfma_f32_16x16x32_bf16(k0, qf[ks], s0, 0, 0, 0);
            s1 = __builtin_amdgcn_mfma_f32_16x16x32_bf16(k1, qf[ks], s1, 0, 0, 0);
        }
        __builtin_amdgcn_s_setprio(0);

        // [C] static-shift softmax, fully lane-local; P packs directly into the A-frag
        float p0[4], p1[4];
        #pragma unroll
        for (int r = 0; r < 4; r++) {
            p0[r] = __expf(s0[r] - M_SHIFT);
            p1[r] = __expf(s1[r] - M_SHIFT);
        }
        l_r += ((p0[0]+p0[1]) + (p0[2]+p0[3])) + ((p1[0]+p1[1]) + (p1[2]+p1[3]));
        bf16x8 af;
        af[0]=f2bf(p0[0]); af[1]=f2bf(p0[1]); af[2]=f2bf(p0[2]); af[3]=f2bf(p0[3]);
        af[4]=f2bf(p1[0]); af[5]=f2bf(p1[1]); af[6]=f2bf(p1[2]); af[7]=f2bf(p1[3]);

        // [D] PV: O[16q][512d] += P * V; B-frags from V-LDS (k pre-permuted to match af)
        const char* Vb = smem + VOFF + buf*32768 + li*64 + vsw;
        __builtin_amdgcn_s_setprio(1);
        #pragma unroll
        for (int j = 0; j < 32; j++) {
            bf16x8 bv = *(const bf16x8*)(Vb + j*1024);
            acc[j] = __builtin_amdgcn_mfma_f32_16x16x32_bf16(af, bv, acc[j], 0, 0, 0);
        }
        __builtin_amdgcn_s_setprio(0);

        // [E] publish: own stage loads arrived (issued a full body ago) + own LDS reads done
        if (t < 31) {
            asm volatile("s_waitcnt vmcnt(0) lgkmcnt(0)" ::: "memory");
            __builtin_amdgcn_s_barrier();
        }
    }

    // ---- epilogue: reduce l across k-groups, store unnormalized O (bf16) + l ----
    l_r += __shfl_xor(l_r, 16);
    l_r += __shfl_xor(l_r, 32);

    bf16_t* op = opart + ((size_t)((s*8 + b)*N_DIM) + q0 + wid*16) * D_DIM;
    #pragma unroll
    for (int j = 0; j < 32; j++)
        #pragma unroll
        for (int r = 0; r < 4; r++)
            op[(size_t)(4*g + r)*D_DIM + j*16 + li] = f2bf(acc[j][r]);

    if (lane < 16) {
        stats[(size_t)(s*8 + b)*N_DIM + q0 + wid*16 + lane] = l_r;
    }
}

// ---------------- Kernel 4: merge splits + residual (exact: same static shift) ----------------
__global__ __launch_bounds__(256) void merge2(
    const bf16_t* __restrict__ opart, const float* __restrict__ stats, float* __restrict__ out)
{
    int row  = (int)((blockIdx.x * blockDim.x + threadIdx.x) >> 6);  // b*2048+n
    int lane = threadIdx.x & 63;
    float l0 = stats[row];
    float l1 = stats[(size_t)16384 + row];
    float rden = 1.f / (l0 + l1);
    size_t base = (size_t)row * D_DIM + lane*8;
    bf16x8 a = *(const bf16x8*)(opart + base);
    bf16x8 c = *(const bf16x8*)(opart + (size_t)16384*D_DIM + base);
    float4 x0 = *(const float4*)(out + base);
    float4 x1 = *(const float4*)(out + base + 4);
    float o[8];
    #pragma unroll
    for (int j = 0; j < 8; j++) o[j] = ((float)a[j] + (float)c[j]) * rden;
    float4 r0 = {x0.x + o[0], x0.y + o[1], x0.z + o[2], x0.w + o[3]};
    float4 r1 = {x1.x + o[4], x1.y + o[5], x1.z + o[6], x1.w + o[7]};
    *(float4*)(out + base)     = r0;
    *(float4*)(out + base + 4) = r1;
}

extern "C" void kernel_launch(void* const* d_in, const int* in_sizes, int n_in,
                              void* d_out, int out_size, void* d_ws, size_t ws_size,
                              hipStream_t stream)
{
    const float* x  = (const float*)d_in[0];
    const float* lw = (const float*)d_in[1];
    const float* lb = (const float*)d_in[2];
    const float* qd = (const float*)d_in[3];
    const float* kd = (const float*)d_in[4];
    const float* vd = (const float*)d_in[5];
    float* out = (float*)d_out;

    // ws layout: qb 16MB | kb 16MB | vT 16MB | opart 32MB | stats 64KB
    const size_t MB = 1024u*1024u;
    char* ws = (char*)d_ws;
    bf16_t* qbuf  = (bf16_t*)(ws);
    bf16_t* kbuf  = (bf16_t*)(ws + 16*MB);
    bf16_t* vTb   = (bf16_t*)(ws + 32*MB);
    bf16_t* opart = (bf16_t*)(ws + 48*MB);
    float*  stats = (float*)(ws + 80*MB);

    hipFuncSetAttribute((const void*)attn6, hipFuncAttributeMaxDynamicSharedMemorySize, SMEM_TOTAL);

    ln_prep<<<4096, 256, 0, stream>>>(x, lw, lb, qd, kd, out, qbuf, kbuf);
    vT_prep<<<dim3(32, 8, 8), 256, 0, stream>>>(out, vd, vTb);
    attn6<<<256, 512, SMEM_TOTAL, stream>>>(qbuf, kbuf, vTb, opart, stats);
    merge2<<<4096, 256, 0, stream>>>(opart, stats, out);
}

// Round 7
// 128.546 us; speedup vs baseline: 3.2135x; 1.0082x over previous
//
#include <hip/hip_runtime.h>
#include <hip/hip_bf16.h>
#include <stdint.h>
#include <math.h>

typedef __bf16 bf16_t;
typedef bf16_t bf16x8 __attribute__((ext_vector_type(8)));
typedef float f32x4 __attribute__((ext_vector_type(4)));

#define B_DIM 8
#define N_DIM 2048
#define D_DIM 512
// (1/sqrt(512)) * log2(e): folded into Q so softmax uses exp2 directly
#define QK_SCALE_L2E 0.063758716f
#define M_SHIFT2 5.7707801635558536f   /* 4 * log2(e); P = exp2(S' - M) = e^(S-4) */

// attn LDS layout (bytes): K dbuf x2, V ring x3  (160 KB exactly)
#define KOFF 0            // 2 x 32768 ([32 k][512 d] bf16, 16B-slot ^ (row&7))
#define VOFF 65536        // 3 x 32768 ([512 d][32 k] bf16, k pre-permuted, slot ^ ((d>>1)&3))
#define SMEM_ATTN 163840

__device__ __forceinline__ bf16_t f2bf(float f) {
    uint32_t u = __builtin_bit_cast(uint32_t, f);
    u += 0x7FFFu + ((u >> 16) & 1u);
    uint16_t h = (uint16_t)(u >> 16);
    return __builtin_bit_cast(bf16_t, h);
}

__device__ __forceinline__ float fexp2(float x) {
    float r;
    asm("v_exp_f32 %0, %1" : "=v"(r) : "v"(x));
    return r;
}

// ---------------- Kernel 1: fused LayerNorm + Q/K prep + permuted V^T ----------------
// grid 256 = 8 b x 32 nblk(64 rows); 512 thr = 8 waves; wave w does rows w*8..w*8+7.
// Writes xn (bf16 if xnb != null, else f32 to xnf), qb (log2e-scaled), kb, and the
// k-permuted bank-salted vT layout via an LDS transpose.
__global__ __launch_bounds__(512) void prep_fused(
    const float* __restrict__ x, const float* __restrict__ w, const float* __restrict__ bia,
    const float* __restrict__ qd, const float* __restrict__ kd, const float* __restrict__ vd,
    bf16_t* __restrict__ xnb, float* __restrict__ xnf,
    bf16_t* __restrict__ qb, bf16_t* __restrict__ kb, bf16_t* __restrict__ vT)
{
    extern __shared__ char pmem[];
    bf16_t (*vt)[512] = (bf16_t(*)[512])pmem;   // [64 n][512 d], 64 KB

    const int bid = blockIdx.x;
    const int b  = bid >> 5;
    const int n0 = (bid & 31) * 64;
    const int tid  = threadIdx.x;
    const int wid  = tid >> 6;
    const int lane = tid & 63;
    const int d    = lane * 8;

    float wv[8], bv[8], qv[8], kv[8], vv[8];
    {
        float4 t;
        t = *(const float4*)(w  + d);     wv[0]=t.x; wv[1]=t.y; wv[2]=t.z; wv[3]=t.w;
        t = *(const float4*)(w  + d + 4); wv[4]=t.x; wv[5]=t.y; wv[6]=t.z; wv[7]=t.w;
        t = *(const float4*)(bia+ d);     bv[0]=t.x; bv[1]=t.y; bv[2]=t.z; bv[3]=t.w;
        t = *(const float4*)(bia+ d + 4); bv[4]=t.x; bv[5]=t.y; bv[6]=t.z; bv[7]=t.w;
        t = *(const float4*)(qd + d);     qv[0]=t.x; qv[1]=t.y; qv[2]=t.z; qv[3]=t.w;
        t = *(const float4*)(qd + d + 4); qv[4]=t.x; qv[5]=t.y; qv[6]=t.z; qv[7]=t.w;
        t = *(const float4*)(kd + d);     kv[0]=t.x; kv[1]=t.y; kv[2]=t.z; kv[3]=t.w;
        t = *(const float4*)(kd + d + 4); kv[4]=t.x; kv[5]=t.y; kv[6]=t.z; kv[7]=t.w;
        t = *(const float4*)(vd + d);     vv[0]=t.x; vv[1]=t.y; vv[2]=t.z; vv[3]=t.w;
        t = *(const float4*)(vd + d + 4); vv[4]=t.x; vv[5]=t.y; vv[6]=t.z; vv[7]=t.w;
    }

    for (int r = 0; r < 8; r++) {
        int nl = wid*8 + r;
        size_t row  = (size_t)b*N_DIM + n0 + nl;
        size_t base = row*D_DIM + d;
        float xv[8];
        {
            float4 a0 = *(const float4*)(x + base);
            float4 a1 = *(const float4*)(x + base + 4);
            xv[0]=a0.x; xv[1]=a0.y; xv[2]=a0.z; xv[3]=a0.w;
            xv[4]=a1.x; xv[5]=a1.y; xv[6]=a1.z; xv[7]=a1.w;
        }
        float s = 0.f, s2 = 0.f;
        #pragma unroll
        for (int j = 0; j < 8; j++) { s += xv[j]; s2 += xv[j]*xv[j]; }
        #pragma unroll
        for (int m = 1; m < 64; m <<= 1) {
            s  += __shfl_xor(s,  m);
            s2 += __shfl_xor(s2, m);
        }
        float mu   = s  * (1.f/512.f);
        float var  = s2 * (1.f/512.f) - mu*mu;
        float rstd = rsqrtf(var + 1e-5f);

        float xo[8];
        bf16x8 qo, ko, xb, vb;
        #pragma unroll
        for (int j = 0; j < 8; j++) {
            float v = (xv[j] - mu) * rstd * wv[j] + bv[j];
            xo[j] = v;
            xb[j] = f2bf(v);
            qo[j] = f2bf(v * qv[j] * QK_SCALE_L2E);
            ko[j] = f2bf(v * kv[j]);
            vb[j] = f2bf(v * vv[j]);
        }
        if (xnb) {
            *(bf16x8*)(xnb + base) = xb;
        } else {
            float4 o0 = {xo[0],xo[1],xo[2],xo[3]};
            float4 o1 = {xo[4],xo[5],xo[6],xo[7]};
            *(float4*)(xnf + base)     = o0;
            *(float4*)(xnf + base + 4) = o1;
        }
        *(bf16x8*)(qb + base) = qo;
        *(bf16x8*)(kb + base) = ko;
        *(bf16x8*)(&vt[nl][d]) = vb;
    }
    __syncthreads();

    // vT output: thread t handles d = t over all 64 n (2 kblks x 4 slots).
    // Slot sp holds logical g = sp ^ ((d>>1)&3): k = {4g..4g+3, 16+4g..16+4g+3}.
    {
        const int dd = tid;
        const int salt = (dd >> 1) & 3;
        bf16_t* vrow = vT + ((size_t)(b*D_DIM + dd))*N_DIM + n0;
        #pragma unroll
        for (int kb2 = 0; kb2 < 2; kb2++) {
            #pragma unroll
            for (int sp = 0; sp < 4; sp++) {
                int gg = sp ^ salt;
                bf16x8 o;
                #pragma unroll
                for (int e = 0; e < 4; e++) o[e]   = vt[kb2*32 + 4*gg + e][dd];
                #pragma unroll
                for (int e = 0; e < 4; e++) o[4+e] = vt[kb2*32 + 16 + 4*gg + e][dd];
                *(bf16x8*)(vrow + kb2*32 + sp*8) = o;
            }
        }
    }
}

// ---------------- Kernel 2: flash attention (split-KV, swapped QK^T, PV-delayed) ----------------
// grid 256: XCD-grouped (batch,split) x 16 qtiles. 512 thr = 8 waves.
// Iter t: stage(t+1) -> QK(t) || PV(t-1) || softmax(t) -> barrier.
// PV is one tile behind (af_prev in regs): its 32 independent MFMA chains fill
// QK's dependent-chain latency; softmax VALU overlaps PV MFMA. V ring-3.
__global__ __launch_bounds__(512, 2) void attn7(
    const bf16_t* __restrict__ qb, const bf16_t* __restrict__ kb,
    const bf16_t* __restrict__ vT, bf16_t* __restrict__ opart, float* __restrict__ stats)
{
    extern __shared__ char smem[];

    const int bid = blockIdx.x;
    const int xcd = bid & 7, jj = bid >> 3;
    const int grp = xcd + 8*(jj >> 4);   // (b,s) group -> one XCD
    const int qt  = jj & 15;
    const int b   = grp >> 1;
    const int s   = grp & 1;
    const int q0  = qt * 128;
    const int n0base = s * 1024;

    const int tid  = threadIdx.x;
    const int wid  = tid >> 6;
    const int lane = tid & 63;
    const int g    = lane >> 4;
    const int li   = lane & 15;

    const bf16_t* kb_b = kb + (size_t)b * N_DIM * D_DIM;
    const bf16_t* vT_b = vT + (size_t)b * D_DIM * N_DIM;

    // Q fragments (loop-invariant): rows q0 + wid*16 + li over all 512 d
    bf16x8 qf[16];
    {
        const bf16_t* qp = qb + ((size_t)(b*N_DIM + q0 + wid*16 + li)) * D_DIM + g*8;
        #pragma unroll
        for (int ks = 0; ks < 16; ks++)
            qf[ks] = *(const bf16x8*)(qp + ks*32);
    }

    f32x4 acc[32];
    const f32x4 zf = {0.f, 0.f, 0.f, 0.f};
    #pragma unroll
    for (int j = 0; j < 32; j++) acc[j] = zf;

    float l_r = 0.f;

    const int Lk = (lane ^ wid) * 8;
    auto stageK = [&](int buf, int t) {
        const int kstart = n0base + t*32;
        char* kdst = smem + KOFF + buf*32768;
        #pragma unroll
        for (int v = 0; v < 4; v++) {
            int row = v*8 + wid;
            const bf16_t* src = kb_b + (size_t)(kstart + row)*D_DIM + Lk;
            __builtin_amdgcn_global_load_lds((const void*)src, (void*)(kdst + row*1024), 16, 0, 0);
        }
    };
    auto stageV = [&](int slot, int t) {
        const int kstart = n0base + t*32;
        char* vdst = smem + VOFF + slot*32768 + wid*4096;
        const int drow = wid*64 + (lane >> 2);
        const bf16_t* src0 = vT_b + (size_t)drow*N_DIM + kstart + (lane & 3)*8;
        #pragma unroll
        for (int v = 0; v < 4; v++) {
            __builtin_amdgcn_global_load_lds((const void*)(src0 + (size_t)(v*16)*N_DIM),
                                             (void*)(vdst + v*1024), 16, 0, 0);
        }
    };

    // prologue: stage tile 0, drain, barrier
    stageK(0, 0);
    stageV(0, 0);
    asm volatile("s_waitcnt vmcnt(0)" ::: "memory");
    __builtin_amdgcn_s_barrier();

    const int sw  = li & 7;
    const int vsw = (g ^ ((li >> 1) & 3)) << 4;

    int snext = 1, sprev = 2;           // (t+1)%3, (t-1)%3
    bf16x8 afp = {};                    // P frag of tile t-1

    #pragma unroll 1
    for (int t = 0; t < 32; ++t) {
        const int kbuf = t & 1;

        // [A] stage next tile (in flight across whole body; confirmed at [E])
        if (t < 31) {
            stageK(kbuf ^ 1, t + 1);
            stageV(snext, t + 1);
        }
        __builtin_amdgcn_sched_barrier(0);

        // [B] swapped QK^T: S^T[32 k][16 q]; lane: q=li, k = 4g+r (s0) / 16+4g+r (s1)
        const char* kr0 = smem + KOFF + kbuf*32768 + li*1024;
        const char* kr1 = kr0 + 16*1024;
        f32x4 s0 = zf, s1 = zf;
        __builtin_amdgcn_s_setprio(1);
        #pragma unroll
        for (int ks = 0; ks < 16; ks++) {
            int phys = (((ks << 2) + g) ^ sw) << 4;
            bf16x8 k0 = *(const bf16x8*)(kr0 + phys);
            bf16x8 k1 = *(const bf16x8*)(kr1 + phys);
            s0 = __builtin_amdgcn_mfma_f32_16x16x32_bf16(k0, qf[ks], s0, 0, 0, 0);
            s1 = __builtin_amdgcn_mfma_f32_16x16x32_bf16(k1, qf[ks], s1, 0, 0, 0);
        }
        __builtin_amdgcn_s_setprio(0);

        // [C] PV(t-1): 32 independent MFMA chains; interleaves with QK/softmax freely
        if (t > 0) {
            const char* Vb = smem + VOFF + sprev*32768 + li*64 + vsw;
            __builtin_amdgcn_s_setprio(1);
            #pragma unroll
            for (int j = 0; j < 32; j++) {
                bf16x8 bv = *(const bf16x8*)(Vb + j*1024);
                acc[j] = __builtin_amdgcn_mfma_f32_16x16x32_bf16(afp, bv, acc[j], 0, 0, 0);
            }
            __builtin_amdgcn_s_setprio(0);
        }

        // [D] softmax(t): P = exp2(S' - 4*log2e), lane-local
        {
            bf16x8 af;
            float la = 0.f, lb2 = 0.f;
            #pragma unroll
            for (int r = 0; r < 4; r++) {
                float e0 = fexp2(s0[r] - M_SHIFT2);
                float e1 = fexp2(s1[r] - M_SHIFT2);
                la += e0; lb2 += e1;
                af[r]   = f2bf(e0);
                af[4+r] = f2bf(e1);
            }
            l_r += la + lb2;
            afp = af;
        }

        // rotate V ring indices
        sprev = (sprev + 1 == 3) ? 0 : sprev + 1;
        snext = (snext + 1 == 3) ? 0 : snext + 1;

        // [E] publish: own stage loads arrived + own LDS reads done
        if (t < 31) {
            asm volatile("s_waitcnt vmcnt(0) lgkmcnt(0)" ::: "memory");
            __builtin_amdgcn_s_barrier();
        }
    }

    // epilogue PV(31): V slot = 31%3 = 1 (== sprev after final rotate)
    {
        const char* Vb = smem + VOFF + sprev*32768 + li*64 + vsw;
        #pragma unroll
        for (int j = 0; j < 32; j++) {
            bf16x8 bv = *(const bf16x8*)(Vb + j*1024);
            acc[j] = __builtin_amdgcn_mfma_f32_16x16x32_bf16(afp, bv, acc[j], 0, 0, 0);
        }
    }

    // reduce l across k-groups; store unnormalized O (bf16) + l
    l_r += __shfl_xor(l_r, 16);
    l_r += __shfl_xor(l_r, 32);

    bf16_t* op = opart + ((size_t)((s*8 + b)*N_DIM) + q0 + wid*16) * D_DIM;
    #pragma unroll
    for (int j = 0; j < 32; j++)
        #pragma unroll
        for (int r = 0; r < 4; r++)
            op[(size_t)(4*g + r)*D_DIM + j*16 + li] = f2bf(acc[j][r]);

    if (lane < 16) {
        stats[(size_t)(s*8 + b)*N_DIM + q0 + wid*16 + lane] = l_r;
    }
}

// ---------------- Kernel 3: merge splits + residual ----------------
__global__ __launch_bounds__(256) void merge3(
    const bf16_t* __restrict__ opart, const float* __restrict__ stats,
    const bf16_t* __restrict__ xnb, float* __restrict__ out)
{
    int row  = (int)((blockIdx.x * blockDim.x + threadIdx.x) >> 6);  // b*2048+n
    int lane = threadIdx.x & 63;
    float l0 = stats[row];
    float l1 = stats[(size_t)16384 + row];
    float rden = 1.f / (l0 + l1);
    size_t base = (size_t)row * D_DIM + lane*8;
    bf16x8 a = *(const bf16x8*)(opart + base);
    bf16x8 c = *(const bf16x8*)(opart + (size_t)16384*D_DIM + base);
    float xv[8];
    if (xnb) {
        bf16x8 xb = *(const bf16x8*)(xnb + base);
        #pragma unroll
        for (int j = 0; j < 8; j++) xv[j] = (float)xb[j];
    } else {
        float4 x0 = *(const float4*)(out + base);
        float4 x1 = *(const float4*)(out + base + 4);
        xv[0]=x0.x; xv[1]=x0.y; xv[2]=x0.z; xv[3]=x0.w;
        xv[4]=x1.x; xv[5]=x1.y; xv[6]=x1.z; xv[7]=x1.w;
    }
    float o[8];
    #pragma unroll
    for (int j = 0; j < 8; j++) o[j] = xv[j] + ((float)a[j] + (float)c[j]) * rden;
    float4 r0 = {o[0], o[1], o[2], o[3]};
    float4 r1 = {o[4], o[5], o[6], o[7]};
    *(float4*)(out + base)     = r0;
    *(float4*)(out + base + 4) = r1;
}

extern "C" void kernel_launch(void* const* d_in, const int* in_sizes, int n_in,
                              void* d_out, int out_size, void* d_ws, size_t ws_size,
                              hipStream_t stream)
{
    const float* x  = (const float*)d_in[0];
    const float* lw = (const float*)d_in[1];
    const float* lb = (const float*)d_in[2];
    const float* qd = (const float*)d_in[3];
    const float* kd = (const float*)d_in[4];
    const float* vd = (const float*)d_in[5];
    float* out = (float*)d_out;

    // ws: qb 16MB | kb 16MB | vT 16MB | opart 32MB | stats 128KB | xnb 16MB (if room)
    const size_t MB = 1024u*1024u;
    char* ws = (char*)d_ws;
    bf16_t* qbuf  = (bf16_t*)(ws);
    bf16_t* kbuf  = (bf16_t*)(ws + 16*MB);
    bf16_t* vTb   = (bf16_t*)(ws + 32*MB);
    bf16_t* opart = (bf16_t*)(ws + 48*MB);
    float*  stats = (float*)(ws + 80*MB);
    bf16_t* xnb   = (ws_size >= 97*MB) ? (bf16_t*)(ws + 81*MB) : nullptr;

    hipFuncSetAttribute((const void*)prep_fused, hipFuncAttributeMaxDynamicSharedMemorySize, 65536);
    hipFuncSetAttribute((const void*)attn7, hipFuncAttributeMaxDynamicSharedMemorySize, SMEM_ATTN);

    prep_fused<<<256, 512, 65536, stream>>>(x, lw, lb, qd, kd, vd, xnb, out, qbuf, kbuf, vTb);
    attn7<<<256, 512, SMEM_ATTN, stream>>>(qbuf, kbuf, vTb, opart, stats);
    merge3<<<4096, 256, 0, stream>>>(opart, stats, xnb, out);
}